// Round 11
// baseline (844.028 us; speedup 1.0000x reference)
//
#include <hip/hip_runtime.h>
#include <math.h>

#define B_ 32
#define S_ 64
#define H_ 300
#define M_ 2048          // B*S
#define EPSF 1e-8f

typedef _Float16 f16;
typedef _Float16 f16x2 __attribute__((ext_vector_type(2)));
typedef _Float16 f16x4 __attribute__((ext_vector_type(4)));
typedef _Float16 f16x8 __attribute__((ext_vector_type(8)));
typedef float f32x4 __attribute__((ext_vector_type(4)));

__device__ __forceinline__ float fsig(float x) {
  return __builtin_amdgcn_rcpf(1.f + __expf(-x));
}
__device__ __forceinline__ float ftanh(float x) {
  return 1.f - 2.f * __builtin_amdgcn_rcpf(__expf(2.f * x) + 1.f);
}

// ---- 4x Whh (1200x300 f32) -> f16 padded [4 g][320 u][320 k] each ----
__global__ __launch_bounds__(256) void k_wh16b(const float* __restrict__ WA,
        const float* __restrict__ WB, const float* __restrict__ WC,
        const float* __restrict__ WD, f16* __restrict__ Dall) {
  int wsel = blockIdx.y;
  const float* W = wsel == 0 ? WA : wsel == 1 ? WB : wsel == 2 ? WC : WD;
  f16* D = Dall + (size_t)wsel * 409600;
  int idx = blockIdx.x * 256 + threadIdx.x;
  if (idx >= 409600) return;
  int g = idx / 102400, rem = idx - g * 102400;
  int u = rem / 320, k = rem - u * 320;
  float v = (u < 300 && k < 300) ? W[((size_t)g * 300 + u) * 300 + k] : 0.f;
  D[idx] = (f16)v;
}

// ---- Wih F+B -> f16 [2432][Kpad]; y=0: ctx (300/320), y=1: agg (160/160) ----
__global__ __launch_bounds__(256) void k_wih16b(const float* __restrict__ cF,
        const float* __restrict__ cB, const float* __restrict__ aF,
        const float* __restrict__ aB, f16* __restrict__ Dc, f16* __restrict__ Da) {
  int z = blockIdx.y;
  int Kreal = z ? 160 : 300, Kpad = z ? 160 : 320;
  const float* WF = z ? aF : cF;
  const float* WB = z ? aB : cB;
  f16* D = z ? Da : Dc;
  int idx = blockIdx.x * 256 + threadIdx.x;
  if (idx >= 2432 * Kpad) return;
  int n = idx / Kpad, k = idx - n * Kpad;
  float v = 0.f;
  if (n < 2400 && k < Kreal) {
    int fb = n >= 1200;
    int nn = n - fb * 1200;
    v = (fb ? WB : WF)[(size_t)nn * Kreal + k];
  }
  D[idx] = (f16)v;
}

// ---- W^2: 6 x (20x300) -> f16 [6][32][320] ----
__global__ __launch_bounds__(256) void k_wsq16(const float* __restrict__ W0,
        const float* __restrict__ W1, const float* __restrict__ W2,
        const float* __restrict__ W3, const float* __restrict__ W4,
        const float* __restrict__ W5, f16* __restrict__ D) {
  int idx = blockIdx.x * 256 + threadIdx.x;
  if (idx >= 61440) return;
  int wi = idx / 10240, rem = idx - wi * 10240;
  int r = rem / 320, k = rem - r * 320;
  float v = 0.f;
  if (r < 20 && k < 300) {
    const float* W = wi == 0 ? W0 : wi == 1 ? W1 : wi == 2 ? W2
                   : wi == 3 ? W3 : wi == 4 ? W4 : W5;
    float w = W[(size_t)r * 300 + k];
    v = w * w;
  }
  D[idx] = (f16)v;
}

// ---- pW1 (600x1200) -> f16 [640][1280], col k = rec*320+u, zero pad ----
__global__ __launch_bounds__(256) void k_w1h16(const float* __restrict__ W1,
        f16* __restrict__ D) {
  int idx = blockIdx.x * 256 + threadIdx.x;
  if (idx >= 819200) return;
  int n = idx / 1280, k = idx - n * 1280;
  int rec = k / 320, u = k - rec * 320;
  float v = (n < 600 && u < 300) ? W1[(size_t)n * 1200 + rec * 300 + u] : 0.f;
  D[idx] = (f16)v;
}

// ---------------- MFMA input projection, F+B fused, scatter to XG2 ----------
__global__ __launch_bounds__(256) void k_projm(const float* __restrict__ A0,
        const float* __restrict__ A1, const int* __restrict__ g0,
        const int* __restrict__ g1, const f16* __restrict__ B16,
        const float* __restrict__ biasF, const float* __restrict__ biasB,
        f16* __restrict__ XG2, int Kreal, int Kpad, int lda) {
  __shared__ f16 As[128][40];
  __shared__ f16 Bs[128][40];
  int tid = threadIdx.x;
  int z = blockIdx.z;
  const float* A = z ? A1 : A0;
  const int* gather = z ? g1 : g0;
  int recbase = z * 2;
  int m0 = blockIdx.x * 128, n0 = blockIdx.y * 128;
  int w = tid >> 6, l = tid & 63, lo = l & 15, hi = l >> 4;
  int srow = tid >> 1, sk = (tid & 1) * 16;
  int sA_s = (m0 + srow) >> 5, sA_b = (m0 + srow) & 31;
  int itemA = sA_b * 64 + sA_s;
  const float* Arow = gather ? (A + (size_t)gather[itemA] * lda)
                             : (A + (size_t)itemA * lda);
  const f16* Brow = B16 + (size_t)(n0 + srow) * Kpad;
  f32x4 acc[2][8] = {};
  int nkt = Kpad >> 5;
  for (int kt = 0; kt < nkt; ++kt) {
    int k0 = kt * 32;
    #pragma unroll
    for (int q = 0; q < 16; q += 4) {
      int k = k0 + sk + q;
      if (k + 4 <= Kreal) {
        float4 v = *(const float4*)(Arow + k);
        As[srow][sk + q + 0] = (f16)v.x; As[srow][sk + q + 1] = (f16)v.y;
        As[srow][sk + q + 2] = (f16)v.z; As[srow][sk + q + 3] = (f16)v.w;
      } else {
        #pragma unroll
        for (int j = 0; j < 4; ++j)
          As[srow][sk + q + j] = (f16)((k + j < Kreal) ? Arow[k + j] : 0.f);
      }
    }
    *(f16x8*)(&Bs[srow][sk]) = *(const f16x8*)(Brow + k0 + sk);
    *(f16x8*)(&Bs[srow][sk + 8]) = *(const f16x8*)(Brow + k0 + sk + 8);
    __syncthreads();
    f16x8 Bf[8];
    #pragma unroll
    for (int nt = 0; nt < 8; ++nt)
      Bf[nt] = *(const f16x8*)(&Bs[nt * 16 + lo][hi * 8]);
    #pragma unroll
    for (int mt = 0; mt < 2; ++mt) {
      f16x8 Af = *(const f16x8*)(&As[w * 32 + mt * 16 + lo][hi * 8]);
      #pragma unroll
      for (int nt = 0; nt < 8; ++nt)
        acc[mt][nt] = __builtin_amdgcn_mfma_f32_16x16x32_f16(Af, Bf[nt], acc[mt][nt], 0, 0, 0);
    }
    __syncthreads();
  }
  int s = (m0 >> 5) + w;
  #pragma unroll
  for (int nt = 0; nt < 8; ++nt) {
    int n = n0 + nt * 16 + lo;
    if (n >= 2400) continue;
    int fb = n >= 1200;
    int nn = n - fb * 1200;
    int g = nn / 300;
    int u = nn - g * 300;
    int jb = u >> 5, ul = u & 31, nh = ul >> 4, lo2 = ul & 15;
    int rec = recbase + fb;
    int t = fb ? 63 - s : s;
    float bias = fb ? biasB[nn] : biasF[nn];
    size_t tbase = ((((size_t)(rec * 64 + t) * 10 + jb) * 4 + g) * 2 + nh) * 512
                   + (size_t)(hi * 16 + lo2) * 4;
    #pragma unroll
    for (int mt = 0; mt < 2; ++mt) {
      f16x4 hv;
      #pragma unroll
      for (int r = 0; r < 4; ++r) hv[r] = (f16)(acc[mt][nt][r] + bias);
      *(f16x4*)(XG2 + tbase + mt * 256) = hv;
    }
  }
}

// ---------------- distributed MFMA LSTM, in-register gates ----------
// 40 blocks = 4 rec x 10 jb; 4 waves = (mt, nh); wave computes ALL 4 gates
// for its (batch-half, u-half) -> i,f,g,o land in same lane's registers.
__global__ __launch_bounds__(256, 1) void k_lstm8(
    const f16* __restrict__ Wh, const f16* __restrict__ XG2,
    unsigned int* __restrict__ Hbuf, unsigned int* __restrict__ O16u,
    unsigned int* __restrict__ flags) {
  int bid = blockIdx.x;
  int rec = bid / 10, jb = bid - rec * 10;
  int tid = threadIdx.x;
  int w = tid >> 6, l = tid & 63, lo = l & 15, hi = l >> 4;
  int mt = w & 1, nh = w >> 1;

  __shared__ f16 Hs[32][328];

  const f16* Wd = Wh + (size_t)(rec & 1) * 409600;
  int u = jb * 32 + nh * 16 + lo;
  f16x8 Bf[4][10];
  #pragma unroll
  for (int g = 0; g < 4; ++g)
    #pragma unroll
    for (int kt = 0; kt < 10; ++kt)
      Bf[g][kt] = *(const f16x8*)(Wd + ((size_t)g * 320 + u) * 320 + kt * 32 + hi * 8);

  float cst[4] = {};
  unsigned int* fl = flags + rec * 160;
  const f16* xgbase = XG2 + ((size_t)(rec * 64) * 10 + jb) * 4096
                      + nh * 512 + mt * 256 + hi * 64 + lo * 4;
  int pidx = jb * 16 + nh * 8 + (lo >> 1);
  bool ev = (lo & 1) == 0;
  bool upad = (u >= 300);

  for (int t = 0; t < 64; ++t) {
    const f16* xt = xgbase + (size_t)t * 40960;
    f16x4 xv[4];
    #pragma unroll
    for (int g = 0; g < 4; ++g) xv[g] = *(const f16x4*)(xt + g * 1024);

    if (t > 0) {
      if (tid < 10) {
        while (__hip_atomic_load(fl + tid * 16, __ATOMIC_RELAXED,
                                 __HIP_MEMORY_SCOPE_AGENT) < (unsigned)t) { }
      }
      __syncthreads();
    }
    {
      unsigned long long* Hg = (unsigned long long*)
          (Hbuf + ((size_t)(t & 1) * 4 + rec) * 5120);
      #pragma unroll
      for (int q = 0; q < 10; ++q) {
        int idx = q * 256 + tid;
        unsigned long long v = __hip_atomic_load(Hg + idx, __ATOMIC_RELAXED,
                                                 __HIP_MEMORY_SCOPE_AGENT);
        int b = idx / 80, rm = idx - b * 80;
        *(unsigned long long*)(&Hs[b][rm * 4]) = v;
      }
    }
    __syncthreads();

    f32x4 acc[4] = {};
    #pragma unroll
    for (int kt = 0; kt < 10; ++kt) {
      f16x8 Af = *(const f16x8*)(&Hs[mt * 16 + lo][kt * 32 + hi * 8]);
      #pragma unroll
      for (int g = 0; g < 4; ++g)
        acc[g] = __builtin_amdgcn_mfma_f32_16x16x32_f16(Af, Bf[g][kt], acc[g], 0, 0, 0);
    }

    int tt = (rec & 1) ? 63 - t : t;
    unsigned int pk[4];
    #pragma unroll
    for (int r = 0; r < 4; ++r) {
      float zi = acc[0][r] + (float)xv[0][r];
      float zf = acc[1][r] + (float)xv[1][r];
      float zg = acc[2][r] + (float)xv[2][r];
      float zo = acc[3][r] + (float)xv[3][r];
      float cn = fsig(zf) * cst[r] + fsig(zi) * ftanh(zg);
      float hn = fsig(zo) * ftanh(cn);
      cst[r] = cn;
      if (upad) hn = 0.f;
      union { f16 h; unsigned short s; } hb; hb.h = (f16)hn;
      int mine = (int)hb.s;
      int oth = __shfl_xor(mine, 1);
      pk[r] = ((unsigned)mine & 0xffffu) | ((unsigned)oth << 16);
    }
    unsigned int* Hw = Hbuf + ((size_t)((t + 1) & 1) * 4 + rec) * 5120;
    if (ev) {
      #pragma unroll
      for (int r = 0; r < 4; ++r)
        __hip_atomic_store(Hw + (mt * 16 + hi * 4 + r) * 160 + pidx, pk[r],
                           __ATOMIC_RELAXED, __HIP_MEMORY_SCOPE_AGENT);
    }
    if (t < 63) {
      asm volatile("s_waitcnt vmcnt(0)" ::: "memory");   // h stores acked at L3
      __syncthreads();
      if (tid == 0)
        __hip_atomic_store(fl + jb * 16, (unsigned)(t + 1), __ATOMIC_RELAXED,
                           __HIP_MEMORY_SCOPE_AGENT);
    }
    if (O16u && ev) {
      #pragma unroll
      for (int r = 0; r < 4; ++r)
        O16u[((size_t)rec * 2048 + (mt * 16 + hi * 4 + r) * 64 + tt) * 160 + pidx] = pk[r];
    }
  }
}

// ---------------- MFMA cosine matrices (f16 out) + fused row/col sums ------
__global__ __launch_bounds__(256) void k_cos2(const f16* __restrict__ O16,
        f16* __restrict__ COS16, float* __restrict__ RS, float* __restrict__ CS) {
  int b = blockIdx.x, d = blockIdx.y;
  int r1 = d, r2 = 2 + d;
  __shared__ f16 As[64][328];
  __shared__ f16 Bs[64][328];
  __shared__ float ninv[2][64];
  __shared__ float ctile[64][68];
  int tid = threadIdx.x;
  int w = tid >> 6, l = tid & 63, lo = l & 15, hi = l >> 4;
  int srow = tid >> 2, sseg = (tid & 3) * 80;
  const f16* ap = O16 + ((size_t)r1 * 2048 + b * 64 + srow) * 320 + sseg;
  const f16* bp = O16 + ((size_t)r2 * 2048 + b * 64 + srow) * 320 + sseg;
  #pragma unroll
  for (int q = 0; q < 80; q += 8) {
    *(f16x8*)(&As[srow][sseg + q]) = *(const f16x8*)(ap + q);
    *(f16x8*)(&Bs[srow][sseg + q]) = *(const f16x8*)(bp + q);
  }
  __syncthreads();
  if (tid < 128) {
    int which = tid >> 6, row = tid & 63;
    float s = 0.f;
    for (int k = 0; k < 320; ++k) {
      float v = which ? (float)Bs[row][k] : (float)As[row][k];
      s += v * v;
    }
    ninv[which][row] = 1.f / sqrtf(s);
  }
  f32x4 acc[4] = {};
  #pragma unroll
  for (int kt = 0; kt < 10; ++kt) {
    f16x8 Af = *(const f16x8*)(&As[w * 16 + lo][kt * 32 + hi * 8]);
    #pragma unroll
    for (int jt = 0; jt < 4; ++jt) {
      f16x8 Bf = *(const f16x8*)(&Bs[jt * 16 + lo][kt * 32 + hi * 8]);
      acc[jt] = __builtin_amdgcn_mfma_f32_16x16x32_f16(Af, Bf, acc[jt], 0, 0, 0);
    }
  }
  __syncthreads();      // ninv ready
  float n1i[4];
  #pragma unroll
  for (int r = 0; r < 4; ++r) n1i[r] = ninv[0][w * 16 + hi * 4 + r];
  #pragma unroll
  for (int jt = 0; jt < 4; ++jt) {
    float n2j = ninv[1][jt * 16 + lo];
    #pragma unroll
    for (int r = 0; r < 4; ++r) {
      int i = w * 16 + hi * 4 + r, j = jt * 16 + lo;
      ctile[i][j] = acc[jt][r] * n1i[r] * n2j;
    }
  }
  __syncthreads();
  unsigned int* op = (unsigned int*)(COS16 + ((size_t)d * 32 + b) * 4096);
  for (int idx = tid; idx < 2048; idx += 256) {
    int i = idx >> 5, jc = idx & 31;
    union { f16x2 h; unsigned int u; } pk;
    pk.h[0] = (f16)ctile[i][jc * 2]; pk.h[1] = (f16)ctile[i][jc * 2 + 1];
    op[idx] = pk.u;
  }
  if (tid < 64) {
    float rs = 0.f;
    for (int k = 0; k < 64; ++k) rs += ctile[tid][k];
    RS[(d * 32 + b) * 64 + tid] = rs;
  } else if (tid < 128) {
    int j = tid - 64;
    float cs = 0.f;
    for (int k = 0; k < 64; ++k) cs += ctile[k][j];
    CS[(d * 32 + b) * 64 + j] = cs;
  }
}

// ---------------- MFMA pairwise match + fused max over i and j ------------
__global__ __launch_bounds__(256) void k_pairf2(const f16* __restrict__ O16,
        const f16* __restrict__ WSQ, float* __restrict__ V1, float* __restrict__ V2) {
  int b = blockIdx.x, d = blockIdx.y;
  __shared__ f16 As[64][328];
  __shared__ f16 Bs[64][328];
  __shared__ float ninv[2][64];
  __shared__ float mjb[64][20];
  __shared__ float mir[4][64][20];
  int tid = threadIdx.x;
  int w = tid >> 6, l = tid & 63, lo = l & 15, hi = l >> 4;
  int srow = tid >> 2, sseg = (tid & 3) * 80;
  const f16* ap = O16 + ((size_t)d * 2048 + b * 64 + srow) * 320 + sseg;
  const f16* bp = O16 + ((size_t)3 * 2048 + b * 64 + srow) * 320 + sseg;
  #pragma unroll
  for (int q = 0; q < 80; q += 8) {
    *(f16x8*)(&As[srow][sseg + q]) = *(const f16x8*)(ap + q);
    *(f16x8*)(&Bs[srow][sseg + q]) = *(const f16x8*)(bp + q);
  }
  __syncthreads();
  if (tid < 128) {
    int which = tid >> 6, row = tid & 63;
    float s = 0.f;
    for (int k = 0; k < 320; ++k) {
      float v = which ? (float)Bs[row][k] : (float)As[row][k];
      s += v * v;
    }
    ninv[which][row] = 1.f / sqrtf(s);
  }
  __syncthreads();
  float n1i[4], n2i[4];
  #pragma unroll
  for (int r = 0; r < 4; ++r) n1i[r] = ninv[0][w * 16 + hi * 4 + r];
  #pragma unroll
  for (int jt = 0; jt < 4; ++jt) n2i[jt] = ninv[1][jt * 16 + lo];

  const f16* Wv = WSQ + (size_t)(4 + d) * 10240;
  for (int lq = 0; lq < 20; ++lq) {
    f32x4 acc[4] = {};
    #pragma unroll
    for (int kt = 0; kt < 10; ++kt) {
      f16x8 a = *(const f16x8*)(&As[w * 16 + lo][kt * 32 + hi * 8]);
      f16x8 wf = *(const f16x8*)(Wv + (size_t)lq * 320 + kt * 32 + hi * 8);
      f16x8 aw = a * wf;
      #pragma unroll
      for (int jt = 0; jt < 4; ++jt) {
        f16x8 bf = *(const f16x8*)(&Bs[jt * 16 + lo][kt * 32 + hi * 8]);
        acc[jt] = __builtin_amdgcn_mfma_f32_16x16x32_f16(aw, bf, acc[jt], 0, 0, 0);
      }
    }
    float mjr[4];
    #pragma unroll
    for (int r = 0; r < 4; ++r) {
      float m = acc[0][r] * n2i[0];
      #pragma unroll
      for (int jt = 1; jt < 4; ++jt) m = fmaxf(m, acc[jt][r] * n2i[jt]);
      mjr[r] = m;
    }
    #pragma unroll
    for (int off = 1; off < 16; off <<= 1)
      #pragma unroll
      for (int r = 0; r < 4; ++r) mjr[r] = fmaxf(mjr[r], __shfl_xor(mjr[r], off));
    if (lo == 0)
      #pragma unroll
      for (int r = 0; r < 4; ++r)
        mjb[w * 16 + hi * 4 + r][lq] = mjr[r] * n1i[r];
    float milo[4];
    #pragma unroll
    for (int jt = 0; jt < 4; ++jt) {
      float m = acc[jt][0] * n1i[0];
      #pragma unroll
      for (int r = 1; r < 4; ++r) m = fmaxf(m, acc[jt][r] * n1i[r]);
      float o16 = __shfl_xor(m, 16);
      float o32 = __shfl_xor(fmaxf(m, o16), 32);
      milo[jt] = fmaxf(fmaxf(m, o16), o32);
    }
    if (hi == 0)
      #pragma unroll
      for (int jt = 0; jt < 4; ++jt)
        mir[w][jt * 16 + lo][lq] = milo[jt] * n2i[jt];
  }
  __syncthreads();
  int offv0 = (d ? 100 : 20);
  for (int idx = tid; idx < 1280; idx += 256) {
    int i = idx / 20, lq = idx - i * 20;
    V1[((size_t)b * 64 + i) * 160 + offv0 + lq] = mjb[i][lq];
    float m = fmaxf(fmaxf(mir[0][i][lq], mir[1][i][lq]),
                    fmaxf(mir[2][i][lq], mir[3][i][lq]));
    V2[((size_t)b * 64 + i) * 160 + offv0 + lq] = m;
  }
}

// ---------------- attention vectors: z=0 mean (MFMA), z=1 max ----------------
__global__ __launch_bounds__(256) void k_attn(const f16* __restrict__ O16,
        const f16* __restrict__ COS16, const float* __restrict__ RS,
        const float* __restrict__ CS, f16* __restrict__ MM16) {
  int b = blockIdx.x, v = blockIdx.y, mode = blockIdx.z;
  int d = v & 1, s2side = v >> 1;
  __shared__ f16 CT[64][72];
  __shared__ f16 ST[320][72];
  __shared__ f16 Cs[64][132];
  __shared__ unsigned int Ss[64][161];
  int tid = threadIdx.x;
  const unsigned int* Cp = (const unsigned int*)(COS16 + ((size_t)d * 32 + b) * 4096);
  int srcrec = s2side ? 0 : 2;
  const unsigned int* Sp = (const unsigned int*)(O16 + ((size_t)srcrec * 2048 + b * 64) * 320);

  if (mode == 0) {
    if (!s2side) {
      for (int idx = tid; idx < 2048; idx += 256) {
        int i = idx >> 5, jc = idx & 31;
        *(unsigned int*)(&CT[i][jc * 2]) = Cp[idx];
      }
    } else {
      for (int idx = tid; idx < 2048; idx += 256) {
        int i = idx >> 5, jc = idx & 31;
        union { unsigned int u; f16x2 h; } pk; pk.u = Cp[idx];
        CT[jc * 2][i] = pk.h[0];
        CT[jc * 2 + 1][i] = pk.h[1];
      }
    }
    for (int idx = tid; idx < 10240; idx += 256) {
      int k = idx / 160, c = idx - k * 160;
      union { unsigned int u; f16x2 h; } pk; pk.u = Sp[idx];
      ST[c * 2][k] = pk.h[0];
      ST[c * 2 + 1][k] = pk.h[1];
    }
    __syncthreads();
    int w = tid >> 6, l = tid & 63, lo = l & 15, hi = l >> 4;
    f32x4 acc[20] = {};
    #pragma unroll
    for (int kt = 0; kt < 2; ++kt) {
      f16x8 Af = *(const f16x8*)(&CT[w * 16 + lo][kt * 32 + hi * 8]);
      #pragma unroll
      for (int nt = 0; nt < 20; ++nt) {
        f16x8 Bf = *(const f16x8*)(&ST[nt * 16 + lo][kt * 32 + hi * 8]);
        acc[nt] = __builtin_amdgcn_mfma_f32_16x16x32_f16(Af, Bf, acc[nt], 0, 0, 0);
      }
    }
    const float* den = s2side ? CS : RS;
    float dv[4];
    #pragma unroll
    for (int r = 0; r < 4; ++r) dv[r] = den[(d * 32 + b) * 64 + w * 16 + hi * 4 + r];
    __syncthreads();
    f16 (*OT)[328] = (f16(*)[328])(&ST[0][0]);
    #pragma unroll
    for (int nt = 0; nt < 20; ++nt)
      #pragma unroll
      for (int r = 0; r < 4; ++r)
        OT[w * 16 + hi * 4 + r][nt * 16 + lo] = (f16)(acc[nt][r] / dv[r]);
    __syncthreads();
    unsigned int* Mp = (unsigned int*)(MM16 + ((size_t)v * 2048 + b * 64) * 320);
    for (int idx = tid; idx < 10240; idx += 256) {
      int m = idx / 160, c = idx - m * 160;
      union { f16x2 h; unsigned int u; } pk;
      pk.h[0] = OT[m][c * 2]; pk.h[1] = OT[m][c * 2 + 1];
      Mp[idx] = pk.u;
    }
  } else {
    for (int idx = tid; idx < 2048; idx += 256) {
      int i = idx >> 5, jc = idx & 31;
      *(unsigned int*)(&Cs[i][jc * 2]) = Cp[idx];
    }
    for (int idx = tid; idx < 10240; idx += 256) {
      int k = idx / 160, c = idx - k * 160;
      Ss[k][c] = Sp[idx];
    }
    __syncthreads();
    unsigned int* Mp = (unsigned int*)(MM16 + ((size_t)(4 + v) * 2048 + b * 64) * 320);
    for (int idx = tid; idx < 10240; idx += 256) {
      int r = idx / 160, c = idx - r * 160;
      f16 cv = s2side ? Cs[0][r] : Cs[r][0];
      union { unsigned int u; f16x2 h; } sv; sv.u = Ss[0][c];
      f16x2 cc; cc[0] = cv; cc[1] = cv;
      f16x2 mx = cc * sv.h;
      for (int inner = 1; inner < 64; ++inner) {
        f16 cv2 = s2side ? Cs[inner][r] : Cs[r][inner];
        sv.u = Ss[inner][c];
        f16x2 c2; c2[0] = cv2; c2[1] = cv2;
        f16x2 p = c2 * sv.h;
        mx[0] = p[0] > mx[0] ? p[0] : mx[0];
        mx[1] = p[1] > mx[1] ? p[1] : mx[1];
      }
      union { f16x2 h; unsigned int u; } o; o.h = mx;
      Mp[idx] = o.u;
    }
  }
}

// ---------------- MFMA full-match (12 variants), f16 inputs ----------------
__global__ __launch_bounds__(256) void k_fmm(const f16* __restrict__ O16,
        const f16* __restrict__ MM16, const f16* __restrict__ WSQ,
        float* __restrict__ V1, float* __restrict__ V2) {
  int ib = blockIdx.x, var = blockIdx.y;
  int tid = threadIdx.x;
  int w = tid >> 6, l = tid & 63, lo = l & 15, hi = l >> 4;
  int mt = w & 1, nt = w >> 1;
  __shared__ f16 Vs1[32][328];
  __shared__ f16 Vs2[32][328];
  __shared__ float zs[3][32][21];

  const f16* s1f = O16;
  const f16* s1b = O16 + (size_t)2048 * 320;
  const f16* s2f = O16 + (size_t)2 * 2048 * 320;
  const f16* s2b = O16 + (size_t)3 * 2048 * 320;
  const f16 *v1b, *v2b;
  int v2fix = 0, v2off = 0, wi, co;
  float* outbase;
  switch (var) {
    case 0:  v1b = s1f; v2b = s2f; v2fix = 1; v2off = 63; wi = 0; outbase = V1; co = 0;   break;
    case 1:  v1b = s1f; v2b = MM16 + (size_t)0 * 655360; wi = 2; outbase = V1; co = 40; break;
    case 2:  v1b = s1f; v2b = MM16 + (size_t)4 * 655360; wi = 3; outbase = V1; co = 60; break;
    case 3:  v1b = s1b; v2b = s2b; v2fix = 1; v2off = 0; wi = 1; outbase = V1; co = 80; break;
    case 4:  v1b = s1b; v2b = MM16 + (size_t)1 * 655360; wi = 2; outbase = V1; co = 120; break;
    case 5:  v1b = s1b; v2b = MM16 + (size_t)5 * 655360; wi = 3; outbase = V1; co = 140; break;
    case 6:  v1b = s2f; v2b = s1f; v2fix = 1; v2off = 63; wi = 0; outbase = V2; co = 0; break;
    case 7:  v1b = s2f; v2b = MM16 + (size_t)2 * 655360; wi = 2; outbase = V2; co = 40; break;
    case 8:  v1b = s2f; v2b = MM16 + (size_t)6 * 655360; wi = 3; outbase = V2; co = 60; break;
    case 9:  v1b = s2b; v2b = s1b; v2fix = 1; v2off = 0; wi = 1; outbase = V2; co = 80; break;
    case 10: v1b = s2b; v2b = MM16 + (size_t)3 * 655360; wi = 2; outbase = V2; co = 120; break;
    default: v1b = s2b; v2b = MM16 + (size_t)7 * 655360; wi = 3; outbase = V2; co = 140; break;
  }
  int srow = tid >> 3;
  int m1 = ib * 32 + srow;
  int m2 = v2fix ? (m1 & ~63) + v2off : m1;
  const unsigned int* r1 = (const unsigned int*)(v1b + (size_t)m1 * 320);
  const unsigned int* r2 = (const unsigned int*)(v2b + (size_t)m2 * 320);
  #pragma unroll
  for (int q = 0; q < 20; ++q) {
    int c = (tid & 7) + q * 8;
    *(unsigned int*)(&Vs1[srow][c * 2]) = r1[c];
    *(unsigned int*)(&Vs2[srow][c * 2]) = r2[c];
  }
  __syncthreads();

  const f16* Wv = WSQ + (size_t)wi * 10240;
  f32x4 acc[3] = {};
  #pragma unroll
  for (int kt = 0; kt < 10; ++kt) {
    f16x8 a1 = *(const f16x8*)(&Vs1[mt * 16 + lo][kt * 32 + hi * 8]);
    f16x8 a2 = *(const f16x8*)(&Vs2[mt * 16 + lo][kt * 32 + hi * 8]);
    f16x8 bf = *(const f16x8*)(Wv + ((size_t)(nt * 16 + lo)) * 320 + kt * 32 + hi * 8);
    acc[0] = __builtin_amdgcn_mfma_f32_16x16x32_f16(a1 * a2, bf, acc[0], 0, 0, 0);
    acc[1] = __builtin_amdgcn_mfma_f32_16x16x32_f16(a1 * a1, bf, acc[1], 0, 0, 0);
    acc[2] = __builtin_amdgcn_mfma_f32_16x16x32_f16(a2 * a2, bf, acc[2], 0, 0, 0);
  }
  #pragma unroll
  for (int pt = 0; pt < 3; ++pt)
    #pragma unroll
    for (int r = 0; r < 4; ++r) {
      int item = mt * 16 + hi * 4 + r, lcol = nt * 16 + lo;
      if (lcol < 20) zs[pt][item][lcol] = acc[pt][r];
    }
  __syncthreads();
  for (int idx = tid; idx < 640; idx += 256) {
    int item = idx / 20, lcol = idx - item * 20;
    float sn = zs[0][item][lcol], sa = zs[1][item][lcol], sb = zs[2][item][lcol];
    float o = sn / (fmaxf(sqrtf(sa), EPSF) * fmaxf(sqrtf(sb), EPSF));
    outbase[(size_t)(ib * 32 + item) * 160 + co + lcol] = o;
  }
}

// ---------------- MFMA hidden layer: XS = tanh(Hfin . W1h^T + b1) ----------
__global__ __launch_bounds__(256) void k_mlpA(const f16* __restrict__ Hfin,
        const f16* __restrict__ W1h, const float* __restrict__ b1,
        float* __restrict__ XS) {
  __shared__ f16 Amat[32][1288];
  int tid = threadIdx.x;
  int n0 = blockIdx.x * 128;
  const unsigned int* Hp = (const unsigned int*)Hfin;
  for (int i = tid; i < 20480; i += 256) {
    int rec = i / 5120, rem = i - rec * 5120;
    int b = rem / 160, uc = rem - b * 160;
    *(unsigned int*)(&Amat[b][rec * 320 + uc * 2]) = Hp[i];
  }
  __syncthreads();
  int w = tid >> 6, l = tid & 63, lo = l & 15, hi = l >> 4;
  f32x4 acc[2][2] = {};
  for (int kt = 0; kt < 40; ++kt) {
    f16x8 Bf[2];
    #pragma unroll
    for (int nt = 0; nt < 2; ++nt) {
      int n = n0 + (w * 2 + nt) * 16 + lo;
      Bf[nt] = *(const f16x8*)(W1h + (size_t)n * 1280 + kt * 32 + hi * 8);
    }
    #pragma unroll
    for (int mt = 0; mt < 2; ++mt) {
      f16x8 Af = *(const f16x8*)(&Amat[mt * 16 + lo][kt * 32 + hi * 8]);
      #pragma unroll
      for (int nt = 0; nt < 2; ++nt)
        acc[mt][nt] = __builtin_amdgcn_mfma_f32_16x16x32_f16(Af, Bf[nt], acc[mt][nt], 0, 0, 0);
    }
  }
  #pragma unroll
  for (int mt = 0; mt < 2; ++mt)
    #pragma unroll
    for (int nt = 0; nt < 2; ++nt) {
      int n = n0 + (w * 2 + nt) * 16 + lo;
      if (n < 600) {
        float bias = b1[n];
        #pragma unroll
        for (int r = 0; r < 4; ++r) {
          int b = mt * 16 + hi * 4 + r;
          XS[(size_t)b * 600 + n] = ftanh(acc[mt][nt][r] + bias);
        }
      }
    }
}

// ---------------- logits + log_softmax ----------------
__global__ __launch_bounds__(64) void k_mlpB(const float* __restrict__ XS,
        const float* __restrict__ W2, const float* __restrict__ b2,
        float* __restrict__ out) {
  int b = blockIdx.x, lane = threadIdx.x;
  float p0 = 0.f, p1 = 0.f;
  for (int k = lane; k < 600; k += 64) {
    float xv = XS[(size_t)b * 600 + k];
    p0 += xv * W2[k];
    p1 += xv * W2[600 + k];
  }
  #pragma unroll
  for (int off = 32; off; off >>= 1) { p0 += __shfl_xor(p0, off); p1 += __shfl_xor(p1, off); }
  if (lane == 0) {
    float l0 = p0 + b2[0], l1 = p1 + b2[1];
    float m = fmaxf(l0, l1);
    float lse = m + logf(expf(l0 - m) + expf(l1 - m));
    out[b * 2 + 0] = l0 - lse;
    out[b * 2 + 1] = l1 - lse;
  }
}

extern "C" void kernel_launch(void* const* d_in, const int* in_sizes, int n_in,
                              void* d_out, int out_size, void* d_ws, size_t ws_size,
                              hipStream_t stream) {
  (void)in_sizes; (void)out_size;
  if (n_in < 25) return;
  const float* emb    = (const float*)d_in[0];
  const float* cWihF  = (const float*)d_in[1];
  const float* cWhhF  = (const float*)d_in[2];
  const float* cbF    = (const float*)d_in[3];
  const float* cWihB  = (const float*)d_in[4];
  const float* cWhhB  = (const float*)d_in[5];
  const float* cbB    = (const float*)d_in[6];
  const float* aWihF  = (const float*)d_in[7];
  const float* aWhhF  = (const float*)d_in[8];
  const float* abF    = (const float*)d_in[9];
  const float* aWihB  = (const float*)d_in[10];
  const float* aWhhB  = (const float*)d_in[11];
  const float* abB    = (const float*)d_in[12];
  const float* WfullF = (const float*)d_in[13];
  const float* WfullB = (const float*)d_in[14];
  const float* WmaxpF = (const float*)d_in[15];
  const float* WmaxpB = (const float*)d_in[16];
  const float* WattnF = (const float*)d_in[17];
  const float* WmaxaF = (const float*)d_in[18];
  const float* pW1    = (const float*)d_in[19];
  const float* pb1    = (const float*)d_in[20];
  const float* pW2    = (const float*)d_in[21];
  const float* pb2    = (const float*)d_in[22];
  const int*   sa     = (const int*)d_in[23];
  const int*   sb     = (const int*)d_in[24];
  float* out = (float*)d_out;
  float* ws = (float*)d_ws;

  // ---- workspace layout (float offsets) ----
  if (ws_size < (size_t)9252608 * 4) return;
  f16*   W1h  = (f16*)(ws + 0);                //  409600 fl (640x1280 f16)
  float* XS   = ws + 409600;                   //   19200
  f16*   B16c = (f16*)(ws + 428800);           //  389120 fl
  f16*   B16a = (f16*)(ws + 817920);           //  194560 fl
  f16*   Wh16 = (f16*)(ws + 1012480);          //  819200 fl
  f16*   WSQ  = (f16*)(ws + 1831680);          //   30720 fl
  unsigned int* Hbuf  = (unsigned int*)(ws + 1862400);  // 40960 u32
  unsigned int* flags = (unsigned int*)(ws + 1903360);  // 1024 fl (adjacent)
  f16*   COS16 = (f16*)(ws + 1904384);         //  131072 fl
  float* RS   = ws + 2035456;                  //    4096
  float* CS   = ws + 2039552;                  //    4096
  float* V1   = ws + 2043648;                  //  327680
  float* V2   = ws + 2371328;                  //  327680
  unsigned int* O16u = (unsigned int*)(ws + 2699008);   // 1310720 fl
  f16*   O16  = (f16*)O16u;
  f16*   XG2  = (f16*)(ws + 4009728);          // 5242880 fl
  f16*   MM16 = XG2;                           //  alias (2621440 fl needed)

  f16* WhCtx = Wh16;
  f16* WhAgg = Wh16 + (size_t)2 * 409600;

  // ---- weight prep ----
  k_wh16b<<<dim3(1600, 4), 256, 0, stream>>>(cWhhF, cWhhB, aWhhF, aWhhB, Wh16);
  k_wih16b<<<dim3(3040, 2), 256, 0, stream>>>(cWihF, cWihB, aWihF, aWihB, B16c, B16a);
  k_wsq16<<<240, 256, 0, stream>>>(WfullF, WfullB, WattnF, WmaxaF, WmaxpF, WmaxpB, WSQ);
  k_w1h16<<<3200, 256, 0, stream>>>(pW1, W1h);

  // ---- context BiLSTM ----
  k_projm<<<dim3(16, 19, 2), 256, 0, stream>>>(emb, emb, sa, sb, B16c, cbF, cbB, XG2, 300, 320, 300);
  hipMemsetAsync(Hbuf, 0, 167936, stream);     // Hbuf + flags
  k_lstm8<<<40, 256, 0, stream>>>(WhCtx, XG2, Hbuf, O16u, flags);

  // ---- matching ----
  k_cos2<<<dim3(32, 2), 256, 0, stream>>>(O16, COS16, RS, CS);
  k_pairf2<<<dim3(32, 2), 256, 0, stream>>>(O16, WSQ, V1, V2);
  k_attn<<<dim3(32, 4, 2), 256, 0, stream>>>(O16, COS16, RS, CS, MM16);
  k_fmm<<<dim3(64, 12), 256, 0, stream>>>(O16, MM16, WSQ, V1, V2);

  // ---- aggregation BiLSTM ----
  k_projm<<<dim3(16, 19, 2), 256, 0, stream>>>(V1, V2, nullptr, nullptr, B16a, abF, abB, XG2, 160, 160, 160);
  hipMemsetAsync(Hbuf, 0, 167936, stream);
  k_lstm8<<<40, 256, 0, stream>>>(WhAgg, XG2, Hbuf, nullptr, flags);

  // ---- prediction head ----
  k_mlpA<<<5, 256, 0, stream>>>((const f16*)Hbuf, W1h, pb1, XS);
  k_mlpB<<<32, 64, 0, stream>>>(XS, pW2, pb2, out);
}

// Round 12
// 710.427 us; speedup vs baseline: 1.1881x; 1.1881x over previous
//
#include <hip/hip_runtime.h>
#include <math.h>

#define B_ 32
#define S_ 64
#define H_ 300
#define M_ 2048          // B*S
#define EPSF 1e-8f

typedef _Float16 f16;
typedef _Float16 f16x2 __attribute__((ext_vector_type(2)));
typedef _Float16 f16x4 __attribute__((ext_vector_type(4)));
typedef _Float16 f16x8 __attribute__((ext_vector_type(8)));
typedef float f32x4 __attribute__((ext_vector_type(4)));

__device__ __forceinline__ float fsig(float x) {
  return __builtin_amdgcn_rcpf(1.f + __expf(-x));
}
__device__ __forceinline__ float ftanh(float x) {
  return 1.f - 2.f * __builtin_amdgcn_rcpf(__expf(2.f * x) + 1.f);
}

// ---- 4x Whh (1200x300 f32) -> f16 padded [4 g][320 u][320 k] each ----
__global__ __launch_bounds__(256) void k_wh16b(const float* __restrict__ WA,
        const float* __restrict__ WB, const float* __restrict__ WC,
        const float* __restrict__ WD, f16* __restrict__ Dall) {
  int wsel = blockIdx.y;
  const float* W = wsel == 0 ? WA : wsel == 1 ? WB : wsel == 2 ? WC : WD;
  f16* D = Dall + (size_t)wsel * 409600;
  int idx = blockIdx.x * 256 + threadIdx.x;
  if (idx >= 409600) return;
  int g = idx / 102400, rem = idx - g * 102400;
  int u = rem / 320, k = rem - u * 320;
  float v = (u < 300 && k < 300) ? W[((size_t)g * 300 + u) * 300 + k] : 0.f;
  D[idx] = (f16)v;
}

// ---- Wih F+B -> f16 [2432][Kpad]; y=0: ctx (300/320), y=1: agg (160/160) ----
__global__ __launch_bounds__(256) void k_wih16b(const float* __restrict__ cF,
        const float* __restrict__ cB, const float* __restrict__ aF,
        const float* __restrict__ aB, f16* __restrict__ Dc, f16* __restrict__ Da) {
  int z = blockIdx.y;
  int Kreal = z ? 160 : 300, Kpad = z ? 160 : 320;
  const float* WF = z ? aF : cF;
  const float* WB = z ? aB : cB;
  f16* D = z ? Da : Dc;
  int idx = blockIdx.x * 256 + threadIdx.x;
  if (idx >= 2432 * Kpad) return;
  int n = idx / Kpad, k = idx - n * Kpad;
  float v = 0.f;
  if (n < 2400 && k < Kreal) {
    int fb = n >= 1200;
    int nn = n - fb * 1200;
    v = (fb ? WB : WF)[(size_t)nn * Kreal + k];
  }
  D[idx] = (f16)v;
}

// ---- W^2: 6 x (20x300) -> f16 [6][32][320] ----
__global__ __launch_bounds__(256) void k_wsq16(const float* __restrict__ W0,
        const float* __restrict__ W1, const float* __restrict__ W2,
        const float* __restrict__ W3, const float* __restrict__ W4,
        const float* __restrict__ W5, f16* __restrict__ D) {
  int idx = blockIdx.x * 256 + threadIdx.x;
  if (idx >= 61440) return;
  int wi = idx / 10240, rem = idx - wi * 10240;
  int r = rem / 320, k = rem - r * 320;
  float v = 0.f;
  if (r < 20 && k < 300) {
    const float* W = wi == 0 ? W0 : wi == 1 ? W1 : wi == 2 ? W2
                   : wi == 3 ? W3 : wi == 4 ? W4 : W5;
    float w = W[(size_t)r * 300 + k];
    v = w * w;
  }
  D[idx] = (f16)v;
}

// ---- pW1 (600x1200) -> f16 [640][1280], col k = rec*320+u, zero pad ----
__global__ __launch_bounds__(256) void k_w1h16(const float* __restrict__ W1,
        f16* __restrict__ D) {
  int idx = blockIdx.x * 256 + threadIdx.x;
  if (idx >= 819200) return;
  int n = idx / 1280, k = idx - n * 1280;
  int rec = k / 320, u = k - rec * 320;
  float v = (n < 600 && u < 300) ? W1[(size_t)n * 1200 + rec * 300 + u] : 0.f;
  D[idx] = (f16)v;
}

// ---------------- MFMA input projection, F+B fused, scatter to XG2 ----------
__global__ __launch_bounds__(256) void k_projm(const float* __restrict__ A0,
        const float* __restrict__ A1, const int* __restrict__ g0,
        const int* __restrict__ g1, const f16* __restrict__ B16,
        const float* __restrict__ biasF, const float* __restrict__ biasB,
        f16* __restrict__ XG2, int Kreal, int Kpad, int lda) {
  __shared__ f16 As[128][40];
  __shared__ f16 Bs[128][40];
  int tid = threadIdx.x;
  int z = blockIdx.z;
  const float* A = z ? A1 : A0;
  const int* gather = z ? g1 : g0;
  int recbase = z * 2;
  int m0 = blockIdx.x * 128, n0 = blockIdx.y * 128;
  int w = tid >> 6, l = tid & 63, lo = l & 15, hi = l >> 4;
  int srow = tid >> 1, sk = (tid & 1) * 16;
  int sA_s = (m0 + srow) >> 5, sA_b = (m0 + srow) & 31;
  int itemA = sA_b * 64 + sA_s;
  const float* Arow = gather ? (A + (size_t)gather[itemA] * lda)
                             : (A + (size_t)itemA * lda);
  const f16* Brow = B16 + (size_t)(n0 + srow) * Kpad;
  f32x4 acc[2][8] = {};
  int nkt = Kpad >> 5;
  for (int kt = 0; kt < nkt; ++kt) {
    int k0 = kt * 32;
    #pragma unroll
    for (int q = 0; q < 16; q += 4) {
      int k = k0 + sk + q;
      if (k + 4 <= Kreal) {
        float4 v = *(const float4*)(Arow + k);
        As[srow][sk + q + 0] = (f16)v.x; As[srow][sk + q + 1] = (f16)v.y;
        As[srow][sk + q + 2] = (f16)v.z; As[srow][sk + q + 3] = (f16)v.w;
      } else {
        #pragma unroll
        for (int j = 0; j < 4; ++j)
          As[srow][sk + q + j] = (f16)((k + j < Kreal) ? Arow[k + j] : 0.f);
      }
    }
    *(f16x8*)(&Bs[srow][sk]) = *(const f16x8*)(Brow + k0 + sk);
    *(f16x8*)(&Bs[srow][sk + 8]) = *(const f16x8*)(Brow + k0 + sk + 8);
    __syncthreads();
    f16x8 Bf[8];
    #pragma unroll
    for (int nt = 0; nt < 8; ++nt)
      Bf[nt] = *(const f16x8*)(&Bs[nt * 16 + lo][hi * 8]);
    #pragma unroll
    for (int mt = 0; mt < 2; ++mt) {
      f16x8 Af = *(const f16x8*)(&As[w * 32 + mt * 16 + lo][hi * 8]);
      #pragma unroll
      for (int nt = 0; nt < 8; ++nt)
        acc[mt][nt] = __builtin_amdgcn_mfma_f32_16x16x32_f16(Af, Bf[nt], acc[mt][nt], 0, 0, 0);
    }
    __syncthreads();
  }
  int s = (m0 >> 5) + w;
  #pragma unroll
  for (int nt = 0; nt < 8; ++nt) {
    int n = n0 + nt * 16 + lo;
    if (n >= 2400) continue;
    int fb = n >= 1200;
    int nn = n - fb * 1200;
    int g = nn / 300;
    int u = nn - g * 300;
    int jb = u >> 5, ul = u & 31, nh = ul >> 4, lo2 = ul & 15;
    int rec = recbase + fb;
    int t = fb ? 63 - s : s;
    float bias = fb ? biasB[nn] : biasF[nn];
    size_t tbase = ((((size_t)(rec * 64 + t) * 10 + jb) * 4 + g) * 2 + nh) * 512
                   + (size_t)(hi * 16 + lo2) * 4;
    #pragma unroll
    for (int mt = 0; mt < 2; ++mt) {
      f16x4 hv;
      #pragma unroll
      for (int r = 0; r < 4; ++r) hv[r] = (f16)(acc[mt][nt][r] + bias);
      *(f16x4*)(XG2 + tbase + mt * 256) = hv;
    }
  }
}

// ---------------- distributed MFMA LSTM, per-producer flag sync ----------
// (proven round-10 structure: 512 threads, 8 waves = (g, nh), zs exchange)
__global__ __launch_bounds__(512, 1) void k_lstm7(
    const f16* __restrict__ Wh, const f16* __restrict__ XG2,
    unsigned int* __restrict__ Hbuf, unsigned int* __restrict__ O16u,
    unsigned int* __restrict__ flags) {
  int bid = blockIdx.x;
  int rec = bid / 10, jb = bid - rec * 10;
  int tid = threadIdx.x;
  int w = tid >> 6, l = tid & 63, lo = l & 15, hi = l >> 4;
  int g = w & 3, nh = w >> 2;

  __shared__ f16 Hs[32][328];
  __shared__ float zs[4][32][33];

  const f16* Wd = Wh + (size_t)(rec & 1) * 409600;
  int u_t = jb * 32 + nh * 16 + lo;
  f16x8 Bf[10];
  #pragma unroll
  for (int kt = 0; kt < 10; ++kt)
    Bf[kt] = *(const f16x8*)(Wd + ((size_t)g * 320 + u_t) * 320 + kt * 32 + hi * 8);

  int cb = tid >> 4, cup = tid & 15;
  int u0c = jb * 32 + cup * 2;
  float c0 = 0.f, c1 = 0.f;
  unsigned int* fl = flags + rec * 160;
  const f16* xgbase = XG2 + ((size_t)(rec * 64) * 10 + jb) * 4096
                      + ((size_t)(g * 2 + nh)) * 512 + l * 4;

  for (int t = 0; t < 64; ++t) {
    const f16* xt = xgbase + (size_t)t * 40960;
    f16x4 xv[2];
    #pragma unroll
    for (int mt = 0; mt < 2; ++mt) xv[mt] = *(const f16x4*)(xt + mt * 256);

    if (t > 0) {
      if (tid < 10) {
        while (__hip_atomic_load(fl + tid * 16, __ATOMIC_RELAXED,
                                 __HIP_MEMORY_SCOPE_AGENT) < (unsigned)t) { }
      }
      __syncthreads();
    }
    {
      unsigned long long* Hg = (unsigned long long*)
          (Hbuf + ((size_t)(t & 1) * 4 + rec) * 5120);
      #pragma unroll
      for (int q = 0; q < 5; ++q) {
        int idx = q * 512 + tid;
        unsigned long long v = __hip_atomic_load(Hg + idx, __ATOMIC_RELAXED,
                                                 __HIP_MEMORY_SCOPE_AGENT);
        int b = idx / 80, rm = idx - b * 80;
        *(unsigned long long*)(&Hs[b][rm * 4]) = v;
      }
    }
    __syncthreads();

    f32x4 acc[2] = {};
    #pragma unroll
    for (int kt = 0; kt < 10; ++kt) {
      #pragma unroll
      for (int mt = 0; mt < 2; ++mt) {
        f16x8 Af = *(const f16x8*)(&Hs[mt * 16 + lo][kt * 32 + hi * 8]);
        acc[mt] = __builtin_amdgcn_mfma_f32_16x16x32_f16(Af, Bf[kt], acc[mt], 0, 0, 0);
      }
    }
    #pragma unroll
    for (int mt = 0; mt < 2; ++mt)
      #pragma unroll
      for (int r = 0; r < 4; ++r)
        zs[g][mt * 16 + hi * 4 + r][nh * 16 + lo] = acc[mt][r] + (float)xv[mt][r];
    __syncthreads();

    int tt = (rec & 1) ? 63 - t : t;
    float h0n, h1n;
    {
      int uu = cup * 2;
      float zi = zs[0][cb][uu], zf = zs[1][cb][uu];
      float zg = zs[2][cb][uu], zo = zs[3][cb][uu];
      float cn = fsig(zf) * c0 + fsig(zi) * ftanh(zg);
      h0n = fsig(zo) * ftanh(cn);
      c0 = cn;
      zi = zs[0][cb][uu + 1]; zf = zs[1][cb][uu + 1];
      zg = zs[2][cb][uu + 1]; zo = zs[3][cb][uu + 1];
      cn = fsig(zf) * c1 + fsig(zi) * ftanh(zg);
      h1n = fsig(zo) * ftanh(cn);
      c1 = cn;
    }
    if (u0c >= 300) { h0n = 0.f; h1n = 0.f; }
    union { f16x2 h; unsigned int u; } pk;
    pk.h[0] = (f16)h0n; pk.h[1] = (f16)h1n;
    unsigned int* Hw = Hbuf + ((size_t)((t + 1) & 1) * 4 + rec) * 5120;
    __hip_atomic_store(Hw + cb * 160 + jb * 16 + cup, pk.u, __ATOMIC_RELAXED,
                       __HIP_MEMORY_SCOPE_AGENT);
    if (t < 63) {
      asm volatile("s_waitcnt vmcnt(0)" ::: "memory");   // h stores acked at L3
      __syncthreads();
      if (tid == 0)
        __hip_atomic_store(fl + jb * 16, (unsigned)(t + 1), __ATOMIC_RELAXED,
                           __HIP_MEMORY_SCOPE_AGENT);
    }
    if (O16u)
      O16u[((size_t)rec * 2048 + cb * 64 + tt) * 160 + jb * 16 + cup] = pk.u;
  }
}

// ---------------- MFMA cosine matrices (f16 out) + fused row/col sums ------
__global__ __launch_bounds__(256) void k_cos2(const f16* __restrict__ O16,
        f16* __restrict__ COS16, float* __restrict__ RS, float* __restrict__ CS) {
  int b = blockIdx.x, d = blockIdx.y;
  int r1 = d, r2 = 2 + d;
  __shared__ f16 As[64][328];
  __shared__ f16 Bs[64][328];
  __shared__ float ninv[2][64];
  __shared__ float ctile[64][68];
  int tid = threadIdx.x;
  int w = tid >> 6, l = tid & 63, lo = l & 15, hi = l >> 4;
  int srow = tid >> 2, sseg = (tid & 3) * 80;
  const f16* ap = O16 + ((size_t)r1 * 2048 + b * 64 + srow) * 320 + sseg;
  const f16* bp = O16 + ((size_t)r2 * 2048 + b * 64 + srow) * 320 + sseg;
  #pragma unroll
  for (int q = 0; q < 80; q += 8) {
    *(f16x8*)(&As[srow][sseg + q]) = *(const f16x8*)(ap + q);
    *(f16x8*)(&Bs[srow][sseg + q]) = *(const f16x8*)(bp + q);
  }
  __syncthreads();
  if (tid < 128) {
    int which = tid >> 6, row = tid & 63;
    float s = 0.f;
    for (int k = 0; k < 320; ++k) {
      float v = which ? (float)Bs[row][k] : (float)As[row][k];
      s += v * v;
    }
    ninv[which][row] = 1.f / sqrtf(s);
  }
  f32x4 acc[4] = {};
  #pragma unroll
  for (int kt = 0; kt < 10; ++kt) {
    f16x8 Af = *(const f16x8*)(&As[w * 16 + lo][kt * 32 + hi * 8]);
    #pragma unroll
    for (int jt = 0; jt < 4; ++jt) {
      f16x8 Bf = *(const f16x8*)(&Bs[jt * 16 + lo][kt * 32 + hi * 8]);
      acc[jt] = __builtin_amdgcn_mfma_f32_16x16x32_f16(Af, Bf, acc[jt], 0, 0, 0);
    }
  }
  __syncthreads();      // ninv ready
  float n1i[4];
  #pragma unroll
  for (int r = 0; r < 4; ++r) n1i[r] = ninv[0][w * 16 + hi * 4 + r];
  #pragma unroll
  for (int jt = 0; jt < 4; ++jt) {
    float n2j = ninv[1][jt * 16 + lo];
    #pragma unroll
    for (int r = 0; r < 4; ++r) {
      int i = w * 16 + hi * 4 + r, j = jt * 16 + lo;
      ctile[i][j] = acc[jt][r] * n1i[r] * n2j;
    }
  }
  __syncthreads();
  unsigned int* op = (unsigned int*)(COS16 + ((size_t)d * 32 + b) * 4096);
  for (int idx = tid; idx < 2048; idx += 256) {
    int i = idx >> 5, jc = idx & 31;
    union { f16x2 h; unsigned int u; } pk;
    pk.h[0] = (f16)ctile[i][jc * 2]; pk.h[1] = (f16)ctile[i][jc * 2 + 1];
    op[idx] = pk.u;
  }
  if (tid < 64) {
    float rs = 0.f;
    for (int k = 0; k < 64; ++k) rs += ctile[tid][k];
    RS[(d * 32 + b) * 64 + tid] = rs;
  } else if (tid < 128) {
    int j = tid - 64;
    float cs = 0.f;
    for (int k = 0; k < 64; ++k) cs += ctile[k][j];
    CS[(d * 32 + b) * 64 + j] = cs;
  }
}

// ---------------- MFMA pairwise match + fused max over i and j ------------
__global__ __launch_bounds__(256) void k_pairf2(const f16* __restrict__ O16,
        const f16* __restrict__ WSQ, float* __restrict__ V1, float* __restrict__ V2) {
  int b = blockIdx.x, d = blockIdx.y;
  __shared__ f16 As[64][328];
  __shared__ f16 Bs[64][328];
  __shared__ float ninv[2][64];
  __shared__ float mjb[64][20];
  __shared__ float mir[4][64][20];
  int tid = threadIdx.x;
  int w = tid >> 6, l = tid & 63, lo = l & 15, hi = l >> 4;
  int srow = tid >> 2, sseg = (tid & 3) * 80;
  const f16* ap = O16 + ((size_t)d * 2048 + b * 64 + srow) * 320 + sseg;
  const f16* bp = O16 + ((size_t)3 * 2048 + b * 64 + srow) * 320 + sseg;
  #pragma unroll
  for (int q = 0; q < 80; q += 8) {
    *(f16x8*)(&As[srow][sseg + q]) = *(const f16x8*)(ap + q);
    *(f16x8*)(&Bs[srow][sseg + q]) = *(const f16x8*)(bp + q);
  }
  __syncthreads();
  if (tid < 128) {
    int which = tid >> 6, row = tid & 63;
    float s = 0.f;
    for (int k = 0; k < 320; ++k) {
      float v = which ? (float)Bs[row][k] : (float)As[row][k];
      s += v * v;
    }
    ninv[which][row] = 1.f / sqrtf(s);
  }
  __syncthreads();
  float n1i[4], n2i[4];
  #pragma unroll
  for (int r = 0; r < 4; ++r) n1i[r] = ninv[0][w * 16 + hi * 4 + r];
  #pragma unroll
  for (int jt = 0; jt < 4; ++jt) n2i[jt] = ninv[1][jt * 16 + lo];

  const f16* Wv = WSQ + (size_t)(4 + d) * 10240;
  for (int lq = 0; lq < 20; ++lq) {
    f32x4 acc[4] = {};
    #pragma unroll
    for (int kt = 0; kt < 10; ++kt) {
      f16x8 a = *(const f16x8*)(&As[w * 16 + lo][kt * 32 + hi * 8]);
      f16x8 wf = *(const f16x8*)(Wv + (size_t)lq * 320 + kt * 32 + hi * 8);
      f16x8 aw = a * wf;
      #pragma unroll
      for (int jt = 0; jt < 4; ++jt) {
        f16x8 bf = *(const f16x8*)(&Bs[jt * 16 + lo][kt * 32 + hi * 8]);
        acc[jt] = __builtin_amdgcn_mfma_f32_16x16x32_f16(aw, bf, acc[jt], 0, 0, 0);
      }
    }
    float mjr[4];
    #pragma unroll
    for (int r = 0; r < 4; ++r) {
      float m = acc[0][r] * n2i[0];
      #pragma unroll
      for (int jt = 1; jt < 4; ++jt) m = fmaxf(m, acc[jt][r] * n2i[jt]);
      mjr[r] = m;
    }
    #pragma unroll
    for (int off = 1; off < 16; off <<= 1)
      #pragma unroll
      for (int r = 0; r < 4; ++r) mjr[r] = fmaxf(mjr[r], __shfl_xor(mjr[r], off));
    if (lo == 0)
      #pragma unroll
      for (int r = 0; r < 4; ++r)
        mjb[w * 16 + hi * 4 + r][lq] = mjr[r] * n1i[r];
    float milo[4];
    #pragma unroll
    for (int jt = 0; jt < 4; ++jt) {
      float m = acc[jt][0] * n1i[0];
      #pragma unroll
      for (int r = 1; r < 4; ++r) m = fmaxf(m, acc[jt][r] * n1i[r]);
      float o16 = __shfl_xor(m, 16);
      float o32 = __shfl_xor(fmaxf(m, o16), 32);
      milo[jt] = fmaxf(fmaxf(m, o16), o32);
    }
    if (hi == 0)
      #pragma unroll
      for (int jt = 0; jt < 4; ++jt)
        mir[w][jt * 16 + lo][lq] = milo[jt] * n2i[jt];
  }
  __syncthreads();
  int offv0 = (d ? 100 : 20);
  for (int idx = tid; idx < 1280; idx += 256) {
    int i = idx / 20, lq = idx - i * 20;
    V1[((size_t)b * 64 + i) * 160 + offv0 + lq] = mjb[i][lq];
    float m = fmaxf(fmaxf(mir[0][i][lq], mir[1][i][lq]),
                    fmaxf(mir[2][i][lq], mir[3][i][lq]));
    V2[((size_t)b * 64 + i) * 160 + offv0 + lq] = m;
  }
}

// ---------------- attention vectors: z=0 mean (MFMA), z=1 max ----------------
__global__ __launch_bounds__(256) void k_attn(const f16* __restrict__ O16,
        const f16* __restrict__ COS16, const float* __restrict__ RS,
        const float* __restrict__ CS, f16* __restrict__ MM16) {
  int b = blockIdx.x, v = blockIdx.y, mode = blockIdx.z;
  int d = v & 1, s2side = v >> 1;
  __shared__ f16 CT[64][72];
  __shared__ f16 ST[320][72];
  __shared__ f16 Cs[64][132];
  __shared__ unsigned int Ss[64][161];
  int tid = threadIdx.x;
  const unsigned int* Cp = (const unsigned int*)(COS16 + ((size_t)d * 32 + b) * 4096);
  int srcrec = s2side ? 0 : 2;
  const unsigned int* Sp = (const unsigned int*)(O16 + ((size_t)srcrec * 2048 + b * 64) * 320);

  if (mode == 0) {
    if (!s2side) {
      for (int idx = tid; idx < 2048; idx += 256) {
        int i = idx >> 5, jc = idx & 31;
        *(unsigned int*)(&CT[i][jc * 2]) = Cp[idx];
      }
    } else {
      for (int idx = tid; idx < 2048; idx += 256) {
        int i = idx >> 5, jc = idx & 31;
        union { unsigned int u; f16x2 h; } pk; pk.u = Cp[idx];
        CT[jc * 2][i] = pk.h[0];
        CT[jc * 2 + 1][i] = pk.h[1];
      }
    }
    for (int idx = tid; idx < 10240; idx += 256) {
      int k = idx / 160, c = idx - k * 160;
      union { unsigned int u; f16x2 h; } pk; pk.u = Sp[idx];
      ST[c * 2][k] = pk.h[0];
      ST[c * 2 + 1][k] = pk.h[1];
    }
    __syncthreads();
    int w = tid >> 6, l = tid & 63, lo = l & 15, hi = l >> 4;
    f32x4 acc[20] = {};
    #pragma unroll
    for (int kt = 0; kt < 2; ++kt) {
      f16x8 Af = *(const f16x8*)(&CT[w * 16 + lo][kt * 32 + hi * 8]);
      #pragma unroll
      for (int nt = 0; nt < 20; ++nt) {
        f16x8 Bf = *(const f16x8*)(&ST[nt * 16 + lo][kt * 32 + hi * 8]);
        acc[nt] = __builtin_amdgcn_mfma_f32_16x16x32_f16(Af, Bf, acc[nt], 0, 0, 0);
      }
    }
    const float* den = s2side ? CS : RS;
    float dv[4];
    #pragma unroll
    for (int r = 0; r < 4; ++r) dv[r] = den[(d * 32 + b) * 64 + w * 16 + hi * 4 + r];
    __syncthreads();
    f16 (*OT)[328] = (f16(*)[328])(&ST[0][0]);
    #pragma unroll
    for (int nt = 0; nt < 20; ++nt)
      #pragma unroll
      for (int r = 0; r < 4; ++r)
        OT[w * 16 + hi * 4 + r][nt * 16 + lo] = (f16)(acc[nt][r] / dv[r]);
    __syncthreads();
    unsigned int* Mp = (unsigned int*)(MM16 + ((size_t)v * 2048 + b * 64) * 320);
    for (int idx = tid; idx < 10240; idx += 256) {
      int m = idx / 160, c = idx - m * 160;
      union { f16x2 h; unsigned int u; } pk;
      pk.h[0] = OT[m][c * 2]; pk.h[1] = OT[m][c * 2 + 1];
      Mp[idx] = pk.u;
    }
  } else {
    for (int idx = tid; idx < 2048; idx += 256) {
      int i = idx >> 5, jc = idx & 31;
      *(unsigned int*)(&Cs[i][jc * 2]) = Cp[idx];
    }
    for (int idx = tid; idx < 10240; idx += 256) {
      int k = idx / 160, c = idx - k * 160;
      Ss[k][c] = Sp[idx];
    }
    __syncthreads();
    unsigned int* Mp = (unsigned int*)(MM16 + ((size_t)(4 + v) * 2048 + b * 64) * 320);
    for (int idx = tid; idx < 10240; idx += 256) {
      int r = idx / 160, c = idx - r * 160;
      f16 cv = s2side ? Cs[0][r] : Cs[r][0];
      union { unsigned int u; f16x2 h; } sv; sv.u = Ss[0][c];
      f16x2 cc; cc[0] = cv; cc[1] = cv;
      f16x2 mx = cc * sv.h;
      for (int inner = 1; inner < 64; ++inner) {
        f16 cv2 = s2side ? Cs[inner][r] : Cs[r][inner];
        sv.u = Ss[inner][c];
        f16x2 c2; c2[0] = cv2; c2[1] = cv2;
        f16x2 p = c2 * sv.h;
        mx[0] = p[0] > mx[0] ? p[0] : mx[0];
        mx[1] = p[1] > mx[1] ? p[1] : mx[1];
      }
      union { f16x2 h; unsigned int u; } o; o.h = mx;
      Mp[idx] = o.u;
    }
  }
}

// ---------------- MFMA full-match (12 variants), f16 inputs ----------------
__global__ __launch_bounds__(256) void k_fmm(const f16* __restrict__ O16,
        const f16* __restrict__ MM16, const f16* __restrict__ WSQ,
        float* __restrict__ V1, float* __restrict__ V2) {
  int ib = blockIdx.x, var = blockIdx.y;
  int tid = threadIdx.x;
  int w = tid >> 6, l = tid & 63, lo = l & 15, hi = l >> 4;
  int mt = w & 1, nt = w >> 1;
  __shared__ f16 Vs1[32][328];
  __shared__ f16 Vs2[32][328];
  __shared__ float zs[3][32][21];

  const f16* s1f = O16;
  const f16* s1b = O16 + (size_t)2048 * 320;
  const f16* s2f = O16 + (size_t)2 * 2048 * 320;
  const f16* s2b = O16 + (size_t)3 * 2048 * 320;
  const f16 *v1b, *v2b;
  int v2fix = 0, v2off = 0, wi, co;
  float* outbase;
  switch (var) {
    case 0:  v1b = s1f; v2b = s2f; v2fix = 1; v2off = 63; wi = 0; outbase = V1; co = 0;   break;
    case 1:  v1b = s1f; v2b = MM16 + (size_t)0 * 655360; wi = 2; outbase = V1; co = 40; break;
    case 2:  v1b = s1f; v2b = MM16 + (size_t)4 * 655360; wi = 3; outbase = V1; co = 60; break;
    case 3:  v1b = s1b; v2b = s2b; v2fix = 1; v2off = 0; wi = 1; outbase = V1; co = 80; break;
    case 4:  v1b = s1b; v2b = MM16 + (size_t)1 * 655360; wi = 2; outbase = V1; co = 120; break;
    case 5:  v1b = s1b; v2b = MM16 + (size_t)5 * 655360; wi = 3; outbase = V1; co = 140; break;
    case 6:  v1b = s2f; v2b = s1f; v2fix = 1; v2off = 63; wi = 0; outbase = V2; co = 0; break;
    case 7:  v1b = s2f; v2b = MM16 + (size_t)2 * 655360; wi = 2; outbase = V2; co = 40; break;
    case 8:  v1b = s2f; v2b = MM16 + (size_t)6 * 655360; wi = 3; outbase = V2; co = 60; break;
    case 9:  v1b = s2b; v2b = s1b; v2fix = 1; v2off = 0; wi = 1; outbase = V2; co = 80; break;
    case 10: v1b = s2b; v2b = MM16 + (size_t)3 * 655360; wi = 2; outbase = V2; co = 120; break;
    default: v1b = s2b; v2b = MM16 + (size_t)7 * 655360; wi = 3; outbase = V2; co = 140; break;
  }
  int srow = tid >> 3;
  int m1 = ib * 32 + srow;
  int m2 = v2fix ? (m1 & ~63) + v2off : m1;
  const unsigned int* r1 = (const unsigned int*)(v1b + (size_t)m1 * 320);
  const unsigned int* r2 = (const unsigned int*)(v2b + (size_t)m2 * 320);
  #pragma unroll
  for (int q = 0; q < 20; ++q) {
    int c = (tid & 7) + q * 8;
    *(unsigned int*)(&Vs1[srow][c * 2]) = r1[c];
    *(unsigned int*)(&Vs2[srow][c * 2]) = r2[c];
  }
  __syncthreads();

  const f16* Wv = WSQ + (size_t)wi * 10240;
  f32x4 acc[3] = {};
  #pragma unroll
  for (int kt = 0; kt < 10; ++kt) {
    f16x8 a1 = *(const f16x8*)(&Vs1[mt * 16 + lo][kt * 32 + hi * 8]);
    f16x8 a2 = *(const f16x8*)(&Vs2[mt * 16 + lo][kt * 32 + hi * 8]);
    f16x8 bf = *(const f16x8*)(Wv + ((size_t)(nt * 16 + lo)) * 320 + kt * 32 + hi * 8);
    acc[0] = __builtin_amdgcn_mfma_f32_16x16x32_f16(a1 * a2, bf, acc[0], 0, 0, 0);
    acc[1] = __builtin_amdgcn_mfma_f32_16x16x32_f16(a1 * a1, bf, acc[1], 0, 0, 0);
    acc[2] = __builtin_amdgcn_mfma_f32_16x16x32_f16(a2 * a2, bf, acc[2], 0, 0, 0);
  }
  #pragma unroll
  for (int pt = 0; pt < 3; ++pt)
    #pragma unroll
    for (int r = 0; r < 4; ++r) {
      int item = mt * 16 + hi * 4 + r, lcol = nt * 16 + lo;
      if (lcol < 20) zs[pt][item][lcol] = acc[pt][r];
    }
  __syncthreads();
  for (int idx = tid; idx < 640; idx += 256) {
    int item = idx / 20, lcol = idx - item * 20;
    float sn = zs[0][item][lcol], sa = zs[1][item][lcol], sb = zs[2][item][lcol];
    float o = sn / (fmaxf(sqrtf(sa), EPSF) * fmaxf(sqrtf(sb), EPSF));
    outbase[(size_t)(ib * 32 + item) * 160 + co + lcol] = o;
  }
}

// ---------------- MFMA hidden layer: XS = tanh(Hfin . W1h^T + b1) ----------
__global__ __launch_bounds__(256) void k_mlpA(const f16* __restrict__ Hfin,
        const f16* __restrict__ W1h, const float* __restrict__ b1,
        float* __restrict__ XS) {
  __shared__ f16 Amat[32][1288];
  int tid = threadIdx.x;
  int n0 = blockIdx.x * 128;
  const unsigned int* Hp = (const unsigned int*)Hfin;
  for (int i = tid; i < 20480; i += 256) {
    int rec = i / 5120, rem = i - rec * 5120;
    int b = rem / 160, uc = rem - b * 160;
    *(unsigned int*)(&Amat[b][rec * 320 + uc * 2]) = Hp[i];
  }
  __syncthreads();
  int w = tid >> 6, l = tid & 63, lo = l & 15, hi = l >> 4;
  f32x4 acc[2][2] = {};
  for (int kt = 0; kt < 40; ++kt) {
    f16x8 Bf[2];
    #pragma unroll
    for (int nt = 0; nt < 2; ++nt) {
      int n = n0 + (w * 2 + nt) * 16 + lo;
      Bf[nt] = *(const f16x8*)(W1h + (size_t)n * 1280 + kt * 32 + hi * 8);
    }
    #pragma unroll
    for (int mt = 0; mt < 2; ++mt) {
      f16x8 Af = *(const f16x8*)(&Amat[mt * 16 + lo][kt * 32 + hi * 8]);
      #pragma unroll
      for (int nt = 0; nt < 2; ++nt)
        acc[mt][nt] = __builtin_amdgcn_mfma_f32_16x16x32_f16(Af, Bf[nt], acc[mt][nt], 0, 0, 0);
    }
  }
  #pragma unroll
  for (int mt = 0; mt < 2; ++mt)
    #pragma unroll
    for (int nt = 0; nt < 2; ++nt) {
      int n = n0 + (w * 2 + nt) * 16 + lo;
      if (n < 600) {
        float bias = b1[n];
        #pragma unroll
        for (int r = 0; r < 4; ++r) {
          int b = mt * 16 + hi * 4 + r;
          XS[(size_t)b * 600 + n] = ftanh(acc[mt][nt][r] + bias);
        }
      }
    }
}

// ---------------- logits + log_softmax ----------------
__global__ __launch_bounds__(64) void k_mlpB(const float* __restrict__ XS,
        const float* __restrict__ W2, const float* __restrict__ b2,
        float* __restrict__ out) {
  int b = blockIdx.x, lane = threadIdx.x;
  float p0 = 0.f, p1 = 0.f;
  for (int k = lane; k < 600; k += 64) {
    float xv = XS[(size_t)b * 600 + k];
    p0 += xv * W2[k];
    p1 += xv * W2[600 + k];
  }
  #pragma unroll
  for (int off = 32; off; off >>= 1) { p0 += __shfl_xor(p0, off); p1 += __shfl_xor(p1, off); }
  if (lane == 0) {
    float l0 = p0 + b2[0], l1 = p1 + b2[1];
    float m = fmaxf(l0, l1);
    float lse = m + logf(expf(l0 - m) + expf(l1 - m));
    out[b * 2 + 0] = l0 - lse;
    out[b * 2 + 1] = l1 - lse;
  }
}

extern "C" void kernel_launch(void* const* d_in, const int* in_sizes, int n_in,
                              void* d_out, int out_size, void* d_ws, size_t ws_size,
                              hipStream_t stream) {
  (void)in_sizes; (void)out_size;
  if (n_in < 25) return;
  const float* emb    = (const float*)d_in[0];
  const float* cWihF  = (const float*)d_in[1];
  const float* cWhhF  = (const float*)d_in[2];
  const float* cbF    = (const float*)d_in[3];
  const float* cWihB  = (const float*)d_in[4];
  const float* cWhhB  = (const float*)d_in[5];
  const float* cbB    = (const float*)d_in[6];
  const float* aWihF  = (const float*)d_in[7];
  const float* aWhhF  = (const float*)d_in[8];
  const float* abF    = (const float*)d_in[9];
  const float* aWihB  = (const float*)d_in[10];
  const float* aWhhB  = (const float*)d_in[11];
  const float* abB    = (const float*)d_in[12];
  const float* WfullF = (const float*)d_in[13];
  const float* WfullB = (const float*)d_in[14];
  const float* WmaxpF = (const float*)d_in[15];
  const float* WmaxpB = (const float*)d_in[16];
  const float* WattnF = (const float*)d_in[17];
  const float* WmaxaF = (const float*)d_in[18];
  const float* pW1    = (const float*)d_in[19];
  const float* pb1    = (const float*)d_in[20];
  const float* pW2    = (const float*)d_in[21];
  const float* pb2    = (const float*)d_in[22];
  const int*   sa     = (const int*)d_in[23];
  const int*   sb     = (const int*)d_in[24];
  float* out = (float*)d_out;
  float* ws = (float*)d_ws;

  // ---- workspace layout (float offsets) ----
  if (ws_size < (size_t)9252608 * 4) return;
  f16*   W1h  = (f16*)(ws + 0);                //  409600 fl (640x1280 f16)
  float* XS   = ws + 409600;                   //   19200
  f16*   B16c = (f16*)(ws + 428800);           //  389120 fl
  f16*   B16a = (f16*)(ws + 817920);           //  194560 fl
  f16*   Wh16 = (f16*)(ws + 1012480);          //  819200 fl
  f16*   WSQ  = (f16*)(ws + 1831680);          //   30720 fl
  unsigned int* Hbuf  = (unsigned int*)(ws + 1862400);  // 40960 u32
  unsigned int* flags = (unsigned int*)(ws + 1903360);  // 1024 fl (adjacent)
  f16*   COS16 = (f16*)(ws + 1904384);         //  131072 fl
  float* RS   = ws + 2035456;                  //    4096
  float* CS   = ws + 2039552;                  //    4096
  float* V1   = ws + 2043648;                  //  327680
  float* V2   = ws + 2371328;                  //  327680
  unsigned int* O16u = (unsigned int*)(ws + 2699008);   // 1310720 fl
  f16*   O16  = (f16*)O16u;
  f16*   XG2  = (f16*)(ws + 4009728);          // 5242880 fl
  f16*   MM16 = XG2;                           //  alias (2621440 fl needed)

  f16* WhCtx = Wh16;
  f16* WhAgg = Wh16 + (size_t)2 * 409600;

  // ---- weight prep ----
  k_wh16b<<<dim3(1600, 4), 256, 0, stream>>>(cWhhF, cWhhB, aWhhF, aWhhB, Wh16);
  k_wih16b<<<dim3(3040, 2), 256, 0, stream>>>(cWihF, cWihB, aWihF, aWihB, B16c, B16a);
  k_wsq16<<<240, 256, 0, stream>>>(WfullF, WfullB, WattnF, WmaxaF, WmaxpF, WmaxpB, WSQ);
  k_w1h16<<<3200, 256, 0, stream>>>(pW1, W1h);

  // ---- context BiLSTM ----
  k_projm<<<dim3(16, 19, 2), 256, 0, stream>>>(emb, emb, sa, sb, B16c, cbF, cbB, XG2, 300, 320, 300);
  hipMemsetAsync(Hbuf, 0, 167936, stream);     // Hbuf + flags
  k_lstm7<<<40, 512, 0, stream>>>(WhCtx, XG2, Hbuf, O16u, flags);

  // ---- matching ----
  k_cos2<<<dim3(32, 2), 256, 0, stream>>>(O16, COS16, RS, CS);
  k_pairf2<<<dim3(32, 2), 256, 0, stream>>>(O16, WSQ, V1, V2);
  k_attn<<<dim3(32, 4, 2), 256, 0, stream>>>(O16, COS16, RS, CS, MM16);
  k_fmm<<<dim3(64, 12), 256, 0, stream>>>(O16, MM16, WSQ, V1, V2);

  // ---- aggregation BiLSTM ----
  k_projm<<<dim3(16, 19, 2), 256, 0, stream>>>(V1, V2, nullptr, nullptr, B16a, abF, abB, XG2, 160, 160, 160);
  hipMemsetAsync(Hbuf, 0, 167936, stream);
  k_lstm7<<<40, 512, 0, stream>>>(WhAgg, XG2, Hbuf, nullptr, flags);

  // ---- prediction head ----
  k_mlpA<<<5, 256, 0, stream>>>((const f16*)Hbuf, W1h, pb1, XS);
  k_mlpB<<<32, 64, 0, stream>>>(XS, pW2, pb2, out);
}

// Round 13
// 639.199 us; speedup vs baseline: 1.3204x; 1.1114x over previous
//
#include <hip/hip_runtime.h>
#include <math.h>

#define B_ 32
#define S_ 64
#define H_ 300
#define M_ 2048          // B*S
#define EPSF 1e-8f

typedef _Float16 f16;
typedef _Float16 f16x2 __attribute__((ext_vector_type(2)));
typedef _Float16 f16x4 __attribute__((ext_vector_type(4)));
typedef _Float16 f16x8 __attribute__((ext_vector_type(8)));
typedef float f32x4 __attribute__((ext_vector_type(4)));

__device__ __forceinline__ float fsig(float x) {
  return __builtin_amdgcn_rcpf(1.f + __expf(-x));
}
__device__ __forceinline__ float ftanh(float x) {
  return 1.f - 2.f * __builtin_amdgcn_rcpf(__expf(2.f * x) + 1.f);
}

// ---- 4x Whh (1200x300 f32) -> f16 padded [4 g][320 u][320 k] each ----
__global__ __launch_bounds__(256) void k_wh16b(const float* __restrict__ WA,
        const float* __restrict__ WB, const float* __restrict__ WC,
        const float* __restrict__ WD, f16* __restrict__ Dall) {
  int wsel = blockIdx.y;
  const float* W = wsel == 0 ? WA : wsel == 1 ? WB : wsel == 2 ? WC : WD;
  f16* D = Dall + (size_t)wsel * 409600;
  int idx = blockIdx.x * 256 + threadIdx.x;
  if (idx >= 409600) return;
  int g = idx / 102400, rem = idx - g * 102400;
  int u = rem / 320, k = rem - u * 320;
  float v = (u < 300 && k < 300) ? W[((size_t)g * 300 + u) * 300 + k] : 0.f;
  D[idx] = (f16)v;
}

// ---- Wih F+B -> f16 [2432][Kpad]; y=0: ctx (300/320), y=1: agg (160/160) ----
__global__ __launch_bounds__(256) void k_wih16b(const float* __restrict__ cF,
        const float* __restrict__ cB, const float* __restrict__ aF,
        const float* __restrict__ aB, f16* __restrict__ Dc, f16* __restrict__ Da) {
  int z = blockIdx.y;
  int Kreal = z ? 160 : 300, Kpad = z ? 160 : 320;
  const float* WF = z ? aF : cF;
  const float* WB = z ? aB : cB;
  f16* D = z ? Da : Dc;
  int idx = blockIdx.x * 256 + threadIdx.x;
  if (idx >= 2432 * Kpad) return;
  int n = idx / Kpad, k = idx - n * Kpad;
  float v = 0.f;
  if (n < 2400 && k < Kreal) {
    int fb = n >= 1200;
    int nn = n - fb * 1200;
    v = (fb ? WB : WF)[(size_t)nn * Kreal + k];
  }
  D[idx] = (f16)v;
}

// ---- W^2: 6 x (20x300) -> f16 [6][32][320] ----
__global__ __launch_bounds__(256) void k_wsq16(const float* __restrict__ W0,
        const float* __restrict__ W1, const float* __restrict__ W2,
        const float* __restrict__ W3, const float* __restrict__ W4,
        const float* __restrict__ W5, f16* __restrict__ D) {
  int idx = blockIdx.x * 256 + threadIdx.x;
  if (idx >= 61440) return;
  int wi = idx / 10240, rem = idx - wi * 10240;
  int r = rem / 320, k = rem - r * 320;
  float v = 0.f;
  if (r < 20 && k < 300) {
    const float* W = wi == 0 ? W0 : wi == 1 ? W1 : wi == 2 ? W2
                   : wi == 3 ? W3 : wi == 4 ? W4 : W5;
    float w = W[(size_t)r * 300 + k];
    v = w * w;
  }
  D[idx] = (f16)v;
}

// ---- pW1 (600x1200) -> f16 [640][1280], col k = rec*320+u, zero pad ----
__global__ __launch_bounds__(256) void k_w1h16(const float* __restrict__ W1,
        f16* __restrict__ D) {
  int idx = blockIdx.x * 256 + threadIdx.x;
  if (idx >= 819200) return;
  int n = idx / 1280, k = idx - n * 1280;
  int rec = k / 320, u = k - rec * 320;
  float v = (n < 600 && u < 300) ? W1[(size_t)n * 1200 + rec * 300 + u] : 0.f;
  D[idx] = (f16)v;
}

// ---------------- MFMA input projection, F+B fused, scatter to XG2 ----------
__global__ __launch_bounds__(256) void k_projm(const float* __restrict__ A0,
        const float* __restrict__ A1, const int* __restrict__ g0,
        const int* __restrict__ g1, const f16* __restrict__ B16,
        const float* __restrict__ biasF, const float* __restrict__ biasB,
        f16* __restrict__ XG2, int Kreal, int Kpad, int lda) {
  __shared__ f16 As[128][40];
  __shared__ f16 Bs[128][40];
  int tid = threadIdx.x;
  int z = blockIdx.z;
  const float* A = z ? A1 : A0;
  const int* gather = z ? g1 : g0;
  int recbase = z * 2;
  int m0 = blockIdx.x * 128, n0 = blockIdx.y * 128;
  int w = tid >> 6, l = tid & 63, lo = l & 15, hi = l >> 4;
  int srow = tid >> 1, sk = (tid & 1) * 16;
  int sA_s = (m0 + srow) >> 5, sA_b = (m0 + srow) & 31;
  int itemA = sA_b * 64 + sA_s;
  const float* Arow = gather ? (A + (size_t)gather[itemA] * lda)
                             : (A + (size_t)itemA * lda);
  const f16* Brow = B16 + (size_t)(n0 + srow) * Kpad;
  f32x4 acc[2][8] = {};
  int nkt = Kpad >> 5;
  for (int kt = 0; kt < nkt; ++kt) {
    int k0 = kt * 32;
    #pragma unroll
    for (int q = 0; q < 16; q += 4) {
      int k = k0 + sk + q;
      if (k + 4 <= Kreal) {
        float4 v = *(const float4*)(Arow + k);
        As[srow][sk + q + 0] = (f16)v.x; As[srow][sk + q + 1] = (f16)v.y;
        As[srow][sk + q + 2] = (f16)v.z; As[srow][sk + q + 3] = (f16)v.w;
      } else {
        #pragma unroll
        for (int j = 0; j < 4; ++j)
          As[srow][sk + q + j] = (f16)((k + j < Kreal) ? Arow[k + j] : 0.f);
      }
    }
    *(f16x8*)(&Bs[srow][sk]) = *(const f16x8*)(Brow + k0 + sk);
    *(f16x8*)(&Bs[srow][sk + 8]) = *(const f16x8*)(Brow + k0 + sk + 8);
    __syncthreads();
    f16x8 Bf[8];
    #pragma unroll
    for (int nt = 0; nt < 8; ++nt)
      Bf[nt] = *(const f16x8*)(&Bs[nt * 16 + lo][hi * 8]);
    #pragma unroll
    for (int mt = 0; mt < 2; ++mt) {
      f16x8 Af = *(const f16x8*)(&As[w * 32 + mt * 16 + lo][hi * 8]);
      #pragma unroll
      for (int nt = 0; nt < 8; ++nt)
        acc[mt][nt] = __builtin_amdgcn_mfma_f32_16x16x32_f16(Af, Bf[nt], acc[mt][nt], 0, 0, 0);
    }
    __syncthreads();
  }
  int s = (m0 >> 5) + w;
  #pragma unroll
  for (int nt = 0; nt < 8; ++nt) {
    int n = n0 + nt * 16 + lo;
    if (n >= 2400) continue;
    int fb = n >= 1200;
    int nn = n - fb * 1200;
    int g = nn / 300;
    int u = nn - g * 300;
    int jb = u >> 5, ul = u & 31, nh = ul >> 4, lo2 = ul & 15;
    int rec = recbase + fb;
    int t = fb ? 63 - s : s;
    float bias = fb ? biasB[nn] : biasF[nn];
    size_t tbase = ((((size_t)(rec * 64 + t) * 10 + jb) * 4 + g) * 2 + nh) * 512
                   + (size_t)(hi * 16 + lo2) * 4;
    #pragma unroll
    for (int mt = 0; mt < 2; ++mt) {
      f16x4 hv;
      #pragma unroll
      for (int r = 0; r < 4; ++r) hv[r] = (f16)(acc[mt][nt][r] + bias);
      *(f16x4*)(XG2 + tbase + mt * 256) = hv;
    }
  }
}

// ---------------- distributed MFMA LSTM, batch-split chains ----------
// 80 blocks = 4 rec x 10 jb x 2 batch-halves. Recurrence is batch-diagonal,
// so each (rec,half) chain is independent: own flags, own Hbuf half.
// 8 waves = (g, nh); per step: 10 KB stage, 10 MFMAs/wave, half gate work.
// Hbuf: [2 par][4 rec][2 half][16 b][160 u32] == [2 par][4 rec][32 b][160].
__global__ __launch_bounds__(512, 1) void k_lstm9(
    const f16* __restrict__ Wh, const f16* __restrict__ XG2,
    unsigned int* __restrict__ Hbuf, unsigned int* __restrict__ O16u,
    unsigned int* __restrict__ flags) {
  int bid = blockIdx.x;
  int rec = bid / 20, rem = bid - rec * 20;
  int jb = rem >> 1, half = rem & 1;
  int tid = threadIdx.x;
  int w = tid >> 6, l = tid & 63, lo = l & 15, hi = l >> 4;
  int g = w & 3, nh = w >> 2;

  __shared__ f16 Hs[16][328];
  __shared__ float zs[4][16][33];

  const f16* Wd = Wh + (size_t)(rec & 1) * 409600;
  int u_t = jb * 32 + nh * 16 + lo;
  f16x8 Bf[10];
  #pragma unroll
  for (int kt = 0; kt < 10; ++kt)
    Bf[kt] = *(const f16x8*)(Wd + ((size_t)g * 320 + u_t) * 320 + kt * 32 + hi * 8);

  int cb = tid >> 5, cu = tid & 31;         // b 0..15, u 0..31
  int u0c = jb * 32 + cu;
  float c0 = 0.f;
  unsigned int* fl = flags + (rec * 2 + half) * 160;
  const f16* xgbase = XG2 + ((size_t)(rec * 64) * 10 + jb) * 4096
                      + ((size_t)(g * 2 + nh)) * 512 + half * 256 + l * 4;
  bool ev = (cu & 1) == 0;
  bool upad = (u0c >= 300);

  for (int t = 0; t < 64; ++t) {
    const f16* xt = xgbase + (size_t)t * 40960;
    f16x4 xv = *(const f16x4*)xt;

    if (t > 0) {
      if (tid < 10) {
        while (__hip_atomic_load(fl + tid * 16, __ATOMIC_RELAXED,
                                 __HIP_MEMORY_SCOPE_AGENT) < (unsigned)t) { }
      }
      __syncthreads();
    }
    // stage this half's h_t (10 KB): coherent u32 loads -> LDS
    {
      unsigned int* Hg = Hbuf + ((size_t)(t & 1) * 8 + rec * 2 + half) * 2560;
      #pragma unroll
      for (int q = 0; q < 5; ++q) {
        int idx = q * 512 + tid;              // 0..2559
        unsigned int v = __hip_atomic_load(Hg + idx, __ATOMIC_RELAXED,
                                           __HIP_MEMORY_SCOPE_AGENT);
        int b = idx / 160, rm = idx - b * 160;
        *(unsigned int*)(&Hs[b][rm * 2]) = v;
      }
    }
    __syncthreads();

    f32x4 acc = {};
    #pragma unroll
    for (int kt = 0; kt < 10; ++kt) {
      f16x8 Af = *(const f16x8*)(&Hs[lo][kt * 32 + hi * 8]);
      acc = __builtin_amdgcn_mfma_f32_16x16x32_f16(Af, Bf[kt], acc, 0, 0, 0);
    }
    #pragma unroll
    for (int r = 0; r < 4; ++r)
      zs[g][hi * 4 + r][nh * 16 + lo] = acc[r] + (float)xv[r];
    __syncthreads();

    int tt = (rec & 1) ? 63 - t : t;
    float hn;
    {
      float zi = zs[0][cb][cu], zf = zs[1][cb][cu];
      float zg = zs[2][cb][cu], zo = zs[3][cb][cu];
      float cn = fsig(zf) * c0 + fsig(zi) * ftanh(zg);
      hn = fsig(zo) * ftanh(cn);
      c0 = cn;
    }
    if (upad) hn = 0.f;
    union { f16 h; unsigned short s; } hb; hb.h = (f16)hn;
    int mine = (int)hb.s;
    int oth = __shfl_xor(mine, 1);
    unsigned int pk = ((unsigned)mine & 0xffffu) | ((unsigned)oth << 16);
    unsigned int* Hw = Hbuf + ((size_t)((t + 1) & 1) * 8 + rec * 2 + half) * 2560;
    if (ev)
      __hip_atomic_store(Hw + cb * 160 + jb * 16 + (cu >> 1), pk,
                         __ATOMIC_RELAXED, __HIP_MEMORY_SCOPE_AGENT);
    if (t < 63) {
      asm volatile("s_waitcnt vmcnt(0)" ::: "memory");   // h stores acked at L3
      __syncthreads();
      if (tid == 0)
        __hip_atomic_store(fl + jb * 16, (unsigned)(t + 1), __ATOMIC_RELAXED,
                           __HIP_MEMORY_SCOPE_AGENT);
    }
    if (O16u && ev)
      O16u[((size_t)rec * 2048 + (half * 16 + cb) * 64 + tt) * 160
           + jb * 16 + (cu >> 1)] = pk;
  }
}

// ---------------- MFMA cosine matrices (f16 out) + fused row/col sums ------
__global__ __launch_bounds__(256) void k_cos2(const f16* __restrict__ O16,
        f16* __restrict__ COS16, float* __restrict__ RS, float* __restrict__ CS) {
  int b = blockIdx.x, d = blockIdx.y;
  int r1 = d, r2 = 2 + d;
  __shared__ f16 As[64][328];
  __shared__ f16 Bs[64][328];
  __shared__ float ninv[2][64];
  __shared__ float ctile[64][68];
  int tid = threadIdx.x;
  int w = tid >> 6, l = tid & 63, lo = l & 15, hi = l >> 4;
  int srow = tid >> 2, sseg = (tid & 3) * 80;
  const f16* ap = O16 + ((size_t)r1 * 2048 + b * 64 + srow) * 320 + sseg;
  const f16* bp = O16 + ((size_t)r2 * 2048 + b * 64 + srow) * 320 + sseg;
  #pragma unroll
  for (int q = 0; q < 80; q += 8) {
    *(f16x8*)(&As[srow][sseg + q]) = *(const f16x8*)(ap + q);
    *(f16x8*)(&Bs[srow][sseg + q]) = *(const f16x8*)(bp + q);
  }
  __syncthreads();
  if (tid < 128) {
    int which = tid >> 6, row = tid & 63;
    float s = 0.f;
    for (int k = 0; k < 320; ++k) {
      float v = which ? (float)Bs[row][k] : (float)As[row][k];
      s += v * v;
    }
    ninv[which][row] = 1.f / sqrtf(s);
  }
  f32x4 acc[4] = {};
  #pragma unroll
  for (int kt = 0; kt < 10; ++kt) {
    f16x8 Af = *(const f16x8*)(&As[w * 16 + lo][kt * 32 + hi * 8]);
    #pragma unroll
    for (int jt = 0; jt < 4; ++jt) {
      f16x8 Bf = *(const f16x8*)(&Bs[jt * 16 + lo][kt * 32 + hi * 8]);
      acc[jt] = __builtin_amdgcn_mfma_f32_16x16x32_f16(Af, Bf, acc[jt], 0, 0, 0);
    }
  }
  __syncthreads();      // ninv ready
  float n1i[4];
  #pragma unroll
  for (int r = 0; r < 4; ++r) n1i[r] = ninv[0][w * 16 + hi * 4 + r];
  #pragma unroll
  for (int jt = 0; jt < 4; ++jt) {
    float n2j = ninv[1][jt * 16 + lo];
    #pragma unroll
    for (int r = 0; r < 4; ++r) {
      int i = w * 16 + hi * 4 + r, j = jt * 16 + lo;
      ctile[i][j] = acc[jt][r] * n1i[r] * n2j;
    }
  }
  __syncthreads();
  unsigned int* op = (unsigned int*)(COS16 + ((size_t)d * 32 + b) * 4096);
  for (int idx = tid; idx < 2048; idx += 256) {
    int i = idx >> 5, jc = idx & 31;
    union { f16x2 h; unsigned int u; } pk;
    pk.h[0] = (f16)ctile[i][jc * 2]; pk.h[1] = (f16)ctile[i][jc * 2 + 1];
    op[idx] = pk.u;
  }
  if (tid < 64) {
    float rs = 0.f;
    for (int k = 0; k < 64; ++k) rs += ctile[tid][k];
    RS[(d * 32 + b) * 64 + tid] = rs;
  } else if (tid < 128) {
    int j = tid - 64;
    float cs = 0.f;
    for (int k = 0; k < 64; ++k) cs += ctile[k][j];
    CS[(d * 32 + b) * 64 + j] = cs;
  }
}

// ---------------- MFMA pairwise match + fused max over i and j ------------
__global__ __launch_bounds__(256) void k_pairf2(const f16* __restrict__ O16,
        const f16* __restrict__ WSQ, float* __restrict__ V1, float* __restrict__ V2) {
  int b = blockIdx.x, d = blockIdx.y;
  __shared__ f16 As[64][328];
  __shared__ f16 Bs[64][328];
  __shared__ float ninv[2][64];
  __shared__ float mjb[64][20];
  __shared__ float mir[4][64][20];
  int tid = threadIdx.x;
  int w = tid >> 6, l = tid & 63, lo = l & 15, hi = l >> 4;
  int srow = tid >> 2, sseg = (tid & 3) * 80;
  const f16* ap = O16 + ((size_t)d * 2048 + b * 64 + srow) * 320 + sseg;
  const f16* bp = O16 + ((size_t)3 * 2048 + b * 64 + srow) * 320 + sseg;
  #pragma unroll
  for (int q = 0; q < 80; q += 8) {
    *(f16x8*)(&As[srow][sseg + q]) = *(const f16x8*)(ap + q);
    *(f16x8*)(&Bs[srow][sseg + q]) = *(const f16x8*)(bp + q);
  }
  __syncthreads();
  if (tid < 128) {
    int which = tid >> 6, row = tid & 63;
    float s = 0.f;
    for (int k = 0; k < 320; ++k) {
      float v = which ? (float)Bs[row][k] : (float)As[row][k];
      s += v * v;
    }
    ninv[which][row] = 1.f / sqrtf(s);
  }
  __syncthreads();
  float n1i[4], n2i[4];
  #pragma unroll
  for (int r = 0; r < 4; ++r) n1i[r] = ninv[0][w * 16 + hi * 4 + r];
  #pragma unroll
  for (int jt = 0; jt < 4; ++jt) n2i[jt] = ninv[1][jt * 16 + lo];

  const f16* Wv = WSQ + (size_t)(4 + d) * 10240;
  for (int lq = 0; lq < 20; ++lq) {
    f32x4 acc[4] = {};
    #pragma unroll
    for (int kt = 0; kt < 10; ++kt) {
      f16x8 a = *(const f16x8*)(&As[w * 16 + lo][kt * 32 + hi * 8]);
      f16x8 wf = *(const f16x8*)(Wv + (size_t)lq * 320 + kt * 32 + hi * 8);
      f16x8 aw = a * wf;
      #pragma unroll
      for (int jt = 0; jt < 4; ++jt) {
        f16x8 bf = *(const f16x8*)(&Bs[jt * 16 + lo][kt * 32 + hi * 8]);
        acc[jt] = __builtin_amdgcn_mfma_f32_16x16x32_f16(aw, bf, acc[jt], 0, 0, 0);
      }
    }
    float mjr[4];
    #pragma unroll
    for (int r = 0; r < 4; ++r) {
      float m = acc[0][r] * n2i[0];
      #pragma unroll
      for (int jt = 1; jt < 4; ++jt) m = fmaxf(m, acc[jt][r] * n2i[jt]);
      mjr[r] = m;
    }
    #pragma unroll
    for (int off = 1; off < 16; off <<= 1)
      #pragma unroll
      for (int r = 0; r < 4; ++r) mjr[r] = fmaxf(mjr[r], __shfl_xor(mjr[r], off));
    if (lo == 0)
      #pragma unroll
      for (int r = 0; r < 4; ++r)
        mjb[w * 16 + hi * 4 + r][lq] = mjr[r] * n1i[r];
    float milo[4];
    #pragma unroll
    for (int jt = 0; jt < 4; ++jt) {
      float m = acc[jt][0] * n1i[0];
      #pragma unroll
      for (int r = 1; r < 4; ++r) m = fmaxf(m, acc[jt][r] * n1i[r]);
      float o16 = __shfl_xor(m, 16);
      float o32 = __shfl_xor(fmaxf(m, o16), 32);
      milo[jt] = fmaxf(fmaxf(m, o16), o32);
    }
    if (hi == 0)
      #pragma unroll
      for (int jt = 0; jt < 4; ++jt)
        mir[w][jt * 16 + lo][lq] = milo[jt] * n2i[jt];
  }
  __syncthreads();
  int offv0 = (d ? 100 : 20);
  for (int idx = tid; idx < 1280; idx += 256) {
    int i = idx / 20, lq = idx - i * 20;
    V1[((size_t)b * 64 + i) * 160 + offv0 + lq] = mjb[i][lq];
    float m = fmaxf(fmaxf(mir[0][i][lq], mir[1][i][lq]),
                    fmaxf(mir[2][i][lq], mir[3][i][lq]));
    V2[((size_t)b * 64 + i) * 160 + offv0 + lq] = m;
  }
}

// ---------------- attention vectors: z=0 mean (MFMA), z=1 max ----------------
__global__ __launch_bounds__(256) void k_attn(const f16* __restrict__ O16,
        const f16* __restrict__ COS16, const float* __restrict__ RS,
        const float* __restrict__ CS, f16* __restrict__ MM16) {
  int b = blockIdx.x, v = blockIdx.y, mode = blockIdx.z;
  int d = v & 1, s2side = v >> 1;
  __shared__ f16 CT[64][72];
  __shared__ f16 ST[320][72];
  __shared__ f16 Cs[64][132];
  __shared__ unsigned int Ss[64][161];
  int tid = threadIdx.x;
  const unsigned int* Cp = (const unsigned int*)(COS16 + ((size_t)d * 32 + b) * 4096);
  int srcrec = s2side ? 0 : 2;
  const unsigned int* Sp = (const unsigned int*)(O16 + ((size_t)srcrec * 2048 + b * 64) * 320);

  if (mode == 0) {
    if (!s2side) {
      for (int idx = tid; idx < 2048; idx += 256) {
        int i = idx >> 5, jc = idx & 31;
        *(unsigned int*)(&CT[i][jc * 2]) = Cp[idx];
      }
    } else {
      for (int idx = tid; idx < 2048; idx += 256) {
        int i = idx >> 5, jc = idx & 31;
        union { unsigned int u; f16x2 h; } pk; pk.u = Cp[idx];
        CT[jc * 2][i] = pk.h[0];
        CT[jc * 2 + 1][i] = pk.h[1];
      }
    }
    for (int idx = tid; idx < 10240; idx += 256) {
      int k = idx / 160, c = idx - k * 160;
      union { unsigned int u; f16x2 h; } pk; pk.u = Sp[idx];
      ST[c * 2][k] = pk.h[0];
      ST[c * 2 + 1][k] = pk.h[1];
    }
    __syncthreads();
    int w = tid >> 6, l = tid & 63, lo = l & 15, hi = l >> 4;
    f32x4 acc[20] = {};
    #pragma unroll
    for (int kt = 0; kt < 2; ++kt) {
      f16x8 Af = *(const f16x8*)(&CT[w * 16 + lo][kt * 32 + hi * 8]);
      #pragma unroll
      for (int nt = 0; nt < 20; ++nt) {
        f16x8 Bf = *(const f16x8*)(&ST[nt * 16 + lo][kt * 32 + hi * 8]);
        acc[nt] = __builtin_amdgcn_mfma_f32_16x16x32_f16(Af, Bf, acc[nt], 0, 0, 0);
      }
    }
    const float* den = s2side ? CS : RS;
    float dv[4];
    #pragma unroll
    for (int r = 0; r < 4; ++r) dv[r] = den[(d * 32 + b) * 64 + w * 16 + hi * 4 + r];
    __syncthreads();
    f16 (*OT)[328] = (f16(*)[328])(&ST[0][0]);
    #pragma unroll
    for (int nt = 0; nt < 20; ++nt)
      #pragma unroll
      for (int r = 0; r < 4; ++r)
        OT[w * 16 + hi * 4 + r][nt * 16 + lo] = (f16)(acc[nt][r] / dv[r]);
    __syncthreads();
    unsigned int* Mp = (unsigned int*)(MM16 + ((size_t)v * 2048 + b * 64) * 320);
    for (int idx = tid; idx < 10240; idx += 256) {
      int m = idx / 160, c = idx - m * 160;
      union { f16x2 h; unsigned int u; } pk;
      pk.h[0] = OT[m][c * 2]; pk.h[1] = OT[m][c * 2 + 1];
      Mp[idx] = pk.u;
    }
  } else {
    for (int idx = tid; idx < 2048; idx += 256) {
      int i = idx >> 5, jc = idx & 31;
      *(unsigned int*)(&Cs[i][jc * 2]) = Cp[idx];
    }
    for (int idx = tid; idx < 10240; idx += 256) {
      int k = idx / 160, c = idx - k * 160;
      Ss[k][c] = Sp[idx];
    }
    __syncthreads();
    unsigned int* Mp = (unsigned int*)(MM16 + ((size_t)(4 + v) * 2048 + b * 64) * 320);
    for (int idx = tid; idx < 10240; idx += 256) {
      int r = idx / 160, c = idx - r * 160;
      f16 cv = s2side ? Cs[0][r] : Cs[r][0];
      union { unsigned int u; f16x2 h; } sv; sv.u = Ss[0][c];
      f16x2 cc; cc[0] = cv; cc[1] = cv;
      f16x2 mx = cc * sv.h;
      for (int inner = 1; inner < 64; ++inner) {
        f16 cv2 = s2side ? Cs[inner][r] : Cs[r][inner];
        sv.u = Ss[inner][c];
        f16x2 c2; c2[0] = cv2; c2[1] = cv2;
        f16x2 p = c2 * sv.h;
        mx[0] = p[0] > mx[0] ? p[0] : mx[0];
        mx[1] = p[1] > mx[1] ? p[1] : mx[1];
      }
      union { f16x2 h; unsigned int u; } o; o.h = mx;
      Mp[idx] = o.u;
    }
  }
}

// ---------------- MFMA full-match (12 variants), f16 inputs ----------------
__global__ __launch_bounds__(256) void k_fmm(const f16* __restrict__ O16,
        const f16* __restrict__ MM16, const f16* __restrict__ WSQ,
        float* __restrict__ V1, float* __restrict__ V2) {
  int ib = blockIdx.x, var = blockIdx.y;
  int tid = threadIdx.x;
  int w = tid >> 6, l = tid & 63, lo = l & 15, hi = l >> 4;
  int mt = w & 1, nt = w >> 1;
  __shared__ f16 Vs1[32][328];
  __shared__ f16 Vs2[32][328];
  __shared__ float zs[3][32][21];

  const f16* s1f = O16;
  const f16* s1b = O16 + (size_t)2048 * 320;
  const f16* s2f = O16 + (size_t)2 * 2048 * 320;
  const f16* s2b = O16 + (size_t)3 * 2048 * 320;
  const f16 *v1b, *v2b;
  int v2fix = 0, v2off = 0, wi, co;
  float* outbase;
  switch (var) {
    case 0:  v1b = s1f; v2b = s2f; v2fix = 1; v2off = 63; wi = 0; outbase = V1; co = 0;   break;
    case 1:  v1b = s1f; v2b = MM16 + (size_t)0 * 655360; wi = 2; outbase = V1; co = 40; break;
    case 2:  v1b = s1f; v2b = MM16 + (size_t)4 * 655360; wi = 3; outbase = V1; co = 60; break;
    case 3:  v1b = s1b; v2b = s2b; v2fix = 1; v2off = 0; wi = 1; outbase = V1; co = 80; break;
    case 4:  v1b = s1b; v2b = MM16 + (size_t)1 * 655360; wi = 2; outbase = V1; co = 120; break;
    case 5:  v1b = s1b; v2b = MM16 + (size_t)5 * 655360; wi = 3; outbase = V1; co = 140; break;
    case 6:  v1b = s2f; v2b = s1f; v2fix = 1; v2off = 63; wi = 0; outbase = V2; co = 0; break;
    case 7:  v1b = s2f; v2b = MM16 + (size_t)2 * 655360; wi = 2; outbase = V2; co = 40; break;
    case 8:  v1b = s2f; v2b = MM16 + (size_t)6 * 655360; wi = 3; outbase = V2; co = 60; break;
    case 9:  v1b = s2b; v2b = s1b; v2fix = 1; v2off = 0; wi = 1; outbase = V2; co = 80; break;
    case 10: v1b = s2b; v2b = MM16 + (size_t)3 * 655360; wi = 2; outbase = V2; co = 120; break;
    default: v1b = s2b; v2b = MM16 + (size_t)7 * 655360; wi = 3; outbase = V2; co = 140; break;
  }
  int srow = tid >> 3;
  int m1 = ib * 32 + srow;
  int m2 = v2fix ? (m1 & ~63) + v2off : m1;
  const unsigned int* r1 = (const unsigned int*)(v1b + (size_t)m1 * 320);
  const unsigned int* r2 = (const unsigned int*)(v2b + (size_t)m2 * 320);
  #pragma unroll
  for (int q = 0; q < 20; ++q) {
    int c = (tid & 7) + q * 8;
    *(unsigned int*)(&Vs1[srow][c * 2]) = r1[c];
    *(unsigned int*)(&Vs2[srow][c * 2]) = r2[c];
  }
  __syncthreads();

  const f16* Wv = WSQ + (size_t)wi * 10240;
  f32x4 acc[3] = {};
  #pragma unroll
  for (int kt = 0; kt < 10; ++kt) {
    f16x8 a1 = *(const f16x8*)(&Vs1[mt * 16 + lo][kt * 32 + hi * 8]);
    f16x8 a2 = *(const f16x8*)(&Vs2[mt * 16 + lo][kt * 32 + hi * 8]);
    f16x8 bf = *(const f16x8*)(Wv + ((size_t)(nt * 16 + lo)) * 320 + kt * 32 + hi * 8);
    acc[0] = __builtin_amdgcn_mfma_f32_16x16x32_f16(a1 * a2, bf, acc[0], 0, 0, 0);
    acc[1] = __builtin_amdgcn_mfma_f32_16x16x32_f16(a1 * a1, bf, acc[1], 0, 0, 0);
    acc[2] = __builtin_amdgcn_mfma_f32_16x16x32_f16(a2 * a2, bf, acc[2], 0, 0, 0);
  }
  #pragma unroll
  for (int pt = 0; pt < 3; ++pt)
    #pragma unroll
    for (int r = 0; r < 4; ++r) {
      int item = mt * 16 + hi * 4 + r, lcol = nt * 16 + lo;
      if (lcol < 20) zs[pt][item][lcol] = acc[pt][r];
    }
  __syncthreads();
  for (int idx = tid; idx < 640; idx += 256) {
    int item = idx / 20, lcol = idx - item * 20;
    float sn = zs[0][item][lcol], sa = zs[1][item][lcol], sb = zs[2][item][lcol];
    float o = sn / (fmaxf(sqrtf(sa), EPSF) * fmaxf(sqrtf(sb), EPSF));
    outbase[(size_t)(ib * 32 + item) * 160 + co + lcol] = o;
  }
}

// ---------------- MFMA hidden layer: XS = tanh(Hfin . W1h^T + b1) ----------
__global__ __launch_bounds__(256) void k_mlpA(const f16* __restrict__ Hfin,
        const f16* __restrict__ W1h, const float* __restrict__ b1,
        float* __restrict__ XS) {
  __shared__ f16 Amat[32][1288];
  int tid = threadIdx.x;
  int n0 = blockIdx.x * 128;
  const unsigned int* Hp = (const unsigned int*)Hfin;
  for (int i = tid; i < 20480; i += 256) {
    int rec = i / 5120, rem = i - rec * 5120;
    int b = rem / 160, uc = rem - b * 160;
    *(unsigned int*)(&Amat[b][rec * 320 + uc * 2]) = Hp[i];
  }
  __syncthreads();
  int w = tid >> 6, l = tid & 63, lo = l & 15, hi = l >> 4;
  f32x4 acc[2][2] = {};
  for (int kt = 0; kt < 40; ++kt) {
    f16x8 Bf[2];
    #pragma unroll
    for (int nt = 0; nt < 2; ++nt) {
      int n = n0 + (w * 2 + nt) * 16 + lo;
      Bf[nt] = *(const f16x8*)(W1h + (size_t)n * 1280 + kt * 32 + hi * 8);
    }
    #pragma unroll
    for (int mt = 0; mt < 2; ++mt) {
      f16x8 Af = *(const f16x8*)(&Amat[mt * 16 + lo][kt * 32 + hi * 8]);
      #pragma unroll
      for (int nt = 0; nt < 2; ++nt)
        acc[mt][nt] = __builtin_amdgcn_mfma_f32_16x16x32_f16(Af, Bf[nt], acc[mt][nt], 0, 0, 0);
    }
  }
  #pragma unroll
  for (int mt = 0; mt < 2; ++mt)
    #pragma unroll
    for (int nt = 0; nt < 2; ++nt) {
      int n = n0 + (w * 2 + nt) * 16 + lo;
      if (n < 600) {
        float bias = b1[n];
        #pragma unroll
        for (int r = 0; r < 4; ++r) {
          int b = mt * 16 + hi * 4 + r;
          XS[(size_t)b * 600 + n] = ftanh(acc[mt][nt][r] + bias);
        }
      }
    }
}

// ---------------- logits + log_softmax ----------------
__global__ __launch_bounds__(64) void k_mlpB(const float* __restrict__ XS,
        const float* __restrict__ W2, const float* __restrict__ b2,
        float* __restrict__ out) {
  int b = blockIdx.x, lane = threadIdx.x;
  float p0 = 0.f, p1 = 0.f;
  for (int k = lane; k < 600; k += 64) {
    float xv = XS[(size_t)b * 600 + k];
    p0 += xv * W2[k];
    p1 += xv * W2[600 + k];
  }
  #pragma unroll
  for (int off = 32; off; off >>= 1) { p0 += __shfl_xor(p0, off); p1 += __shfl_xor(p1, off); }
  if (lane == 0) {
    float l0 = p0 + b2[0], l1 = p1 + b2[1];
    float m = fmaxf(l0, l1);
    float lse = m + logf(expf(l0 - m) + expf(l1 - m));
    out[b * 2 + 0] = l0 - lse;
    out[b * 2 + 1] = l1 - lse;
  }
}

extern "C" void kernel_launch(void* const* d_in, const int* in_sizes, int n_in,
                              void* d_out, int out_size, void* d_ws, size_t ws_size,
                              hipStream_t stream) {
  (void)in_sizes; (void)out_size;
  if (n_in < 25) return;
  const float* emb    = (const float*)d_in[0];
  const float* cWihF  = (const float*)d_in[1];
  const float* cWhhF  = (const float*)d_in[2];
  const float* cbF    = (const float*)d_in[3];
  const float* cWihB  = (const float*)d_in[4];
  const float* cWhhB  = (const float*)d_in[5];
  const float* cbB    = (const float*)d_in[6];
  const float* aWihF  = (const float*)d_in[7];
  const float* aWhhF  = (const float*)d_in[8];
  const float* abF    = (const float*)d_in[9];
  const float* aWihB  = (const float*)d_in[10];
  const float* aWhhB  = (const float*)d_in[11];
  const float* abB    = (const float*)d_in[12];
  const float* WfullF = (const float*)d_in[13];
  const float* WfullB = (const float*)d_in[14];
  const float* WmaxpF = (const float*)d_in[15];
  const float* WmaxpB = (const float*)d_in[16];
  const float* WattnF = (const float*)d_in[17];
  const float* WmaxaF = (const float*)d_in[18];
  const float* pW1    = (const float*)d_in[19];
  const float* pb1    = (const float*)d_in[20];
  const float* pW2    = (const float*)d_in[21];
  const float* pb2    = (const float*)d_in[22];
  const int*   sa     = (const int*)d_in[23];
  const int*   sb     = (const int*)d_in[24];
  float* out = (float*)d_out;
  float* ws = (float*)d_ws;

  // ---- workspace layout (float offsets) ----
  if (ws_size < (size_t)9253632 * 4) return;
  f16*   W1h  = (f16*)(ws + 0);                //  409600 fl (640x1280 f16)
  float* XS   = ws + 409600;                   //   19200
  f16*   B16c = (f16*)(ws + 428800);           //  389120 fl
  f16*   B16a = (f16*)(ws + 817920);           //  194560 fl
  f16*   Wh16 = (f16*)(ws + 1012480);          //  819200 fl
  f16*   WSQ  = (f16*)(ws + 1831680);          //   30720 fl
  unsigned int* Hbuf  = (unsigned int*)(ws + 1862400);  // 40960 u32
  unsigned int* flags = (unsigned int*)(ws + 1903360);  // 2048 fl (8 chains x 160)
  f16*   COS16 = (f16*)(ws + 1905408);         //  131072 fl
  float* RS   = ws + 2036480;                  //    4096
  float* CS   = ws + 2040576;                  //    4096
  float* V1   = ws + 2044672;                  //  327680
  float* V2   = ws + 2372352;                  //  327680
  unsigned int* O16u = (unsigned int*)(ws + 2700032);   // 1310720 fl
  f16*   O16  = (f16*)O16u;
  f16*   XG2  = (f16*)(ws + 4010752);          // 5242880 fl
  f16*   MM16 = XG2;                           //  alias (2621440 fl needed)

  f16* WhCtx = Wh16;
  f16* WhAgg = Wh16 + (size_t)2 * 409600;

  // ---- weight prep ----
  k_wh16b<<<dim3(1600, 4), 256, 0, stream>>>(cWhhF, cWhhB, aWhhF, aWhhB, Wh16);
  k_wih16b<<<dim3(3040, 2), 256, 0, stream>>>(cWihF, cWihB, aWihF, aWihB, B16c, B16a);
  k_wsq16<<<240, 256, 0, stream>>>(WfullF, WfullB, WattnF, WmaxaF, WmaxpF, WmaxpB, WSQ);
  k_w1h16<<<3200, 256, 0, stream>>>(pW1, W1h);

  // ---- context BiLSTM ----
  k_projm<<<dim3(16, 19, 2), 256, 0, stream>>>(emb, emb, sa, sb, B16c, cbF, cbB, XG2, 300, 320, 300);
  hipMemsetAsync(Hbuf, 0, 172032, stream);     // Hbuf + flags
  k_lstm9<<<80, 512, 0, stream>>>(WhCtx, XG2, Hbuf, O16u, flags);

  // ---- matching ----
  k_cos2<<<dim3(32, 2), 256, 0, stream>>>(O16, COS16, RS, CS);
  k_pairf2<<<dim3(32, 2), 256, 0, stream>>>(O16, WSQ, V1, V2);
  k_attn<<<dim3(32, 4, 2), 256, 0, stream>>>(O16, COS16, RS, CS, MM16);
  k_fmm<<<dim3(64, 12), 256, 0, stream>>>(O16, MM16, WSQ, V1, V2);

  // ---- aggregation BiLSTM ----
  k_projm<<<dim3(16, 19, 2), 256, 0, stream>>>(V1, V2, nullptr, nullptr, B16a, abF, abB, XG2, 160, 160, 160);
  hipMemsetAsync(Hbuf, 0, 172032, stream);
  k_lstm9<<<80, 512, 0, stream>>>(WhAgg, XG2, Hbuf, nullptr, flags);

  // ---- prediction head ----
  k_mlpA<<<5, 256, 0, stream>>>((const f16*)Hbuf, W1h, pb1, XS);
  k_mlpB<<<32, 64, 0, stream>>>(XS, pW2, pb2, out);
}

// Round 14
// 535.010 us; speedup vs baseline: 1.5776x; 1.1947x over previous
//
#include <hip/hip_runtime.h>
#include <math.h>

#define B_ 32
#define S_ 64
#define H_ 300
#define M_ 2048          // B*S
#define EPSF 1e-8f

typedef _Float16 f16;
typedef _Float16 f16x2 __attribute__((ext_vector_type(2)));
typedef _Float16 f16x4 __attribute__((ext_vector_type(4)));
typedef _Float16 f16x8 __attribute__((ext_vector_type(8)));
typedef float f32x4 __attribute__((ext_vector_type(4)));

__device__ __forceinline__ float fsig(float x) {
  return __builtin_amdgcn_rcpf(1.f + __expf(-x));
}
__device__ __forceinline__ float ftanh(float x) {
  return 1.f - 2.f * __builtin_amdgcn_rcpf(__expf(2.f * x) + 1.f);
}

// ---------------- unified weight prep (all conversions in one launch) ------
// [0,1638400): Whh x4 -> f16 [4 dirsel][4 g][320][320]
// [1638400,2416640): ctx Wih F+B -> [2432][320]
// [2416640,2805760): agg Wih F+B -> [2432][160]
// [2805760,2867200): W^2 x6 -> [6][32][320]
// [2867200,3686400): pW1 -> [640][1280]
__global__ __launch_bounds__(256) void k_prep(
        const float* __restrict__ cWhhF, const float* __restrict__ cWhhB,
        const float* __restrict__ aWhhF, const float* __restrict__ aWhhB,
        const float* __restrict__ cWihF, const float* __restrict__ cWihB,
        const float* __restrict__ aWihF, const float* __restrict__ aWihB,
        const float* __restrict__ W0, const float* __restrict__ W1,
        const float* __restrict__ W2, const float* __restrict__ W3,
        const float* __restrict__ W4, const float* __restrict__ W5,
        const float* __restrict__ pW1,
        f16* __restrict__ Wh16, f16* __restrict__ B16c, f16* __restrict__ B16a,
        f16* __restrict__ WSQ, f16* __restrict__ W1h) {
  int idx = blockIdx.x * 256 + threadIdx.x;
  if (idx < 1638400) {
    int wsel = idx / 409600, rem0 = idx - wsel * 409600;
    const float* W = wsel == 0 ? cWhhF : wsel == 1 ? cWhhB : wsel == 2 ? aWhhF : aWhhB;
    int g = rem0 / 102400, rem = rem0 - g * 102400;
    int u = rem / 320, k = rem - u * 320;
    float v = (u < 300 && k < 300) ? W[((size_t)g * 300 + u) * 300 + k] : 0.f;
    Wh16[idx] = (f16)v;
  } else if (idx < 2416640) {
    int i2 = idx - 1638400;
    int n = i2 / 320, k = i2 - n * 320;
    float v = 0.f;
    if (n < 2400 && k < 300) {
      int fb = n >= 1200;
      int nn = n - fb * 1200;
      v = (fb ? cWihB : cWihF)[(size_t)nn * 300 + k];
    }
    B16c[i2] = (f16)v;
  } else if (idx < 2805760) {
    int i2 = idx - 2416640;
    int n = i2 / 160, k = i2 - n * 160;
    float v = 0.f;
    if (n < 2400) {
      int fb = n >= 1200;
      int nn = n - fb * 1200;
      v = (fb ? aWihB : aWihF)[(size_t)nn * 160 + k];
    }
    B16a[i2] = (f16)v;
  } else if (idx < 2867200) {
    int i2 = idx - 2805760;
    int wi = i2 / 10240, rem = i2 - wi * 10240;
    int r = rem / 320, k = rem - r * 320;
    float v = 0.f;
    if (r < 20 && k < 300) {
      const float* W = wi == 0 ? W0 : wi == 1 ? W1 : wi == 2 ? W2
                     : wi == 3 ? W3 : wi == 4 ? W4 : W5;
      float w = W[(size_t)r * 300 + k];
      v = w * w;
    }
    WSQ[i2] = (f16)v;
  } else if (idx < 3686400) {
    int i2 = idx - 2867200;
    int n = i2 / 1280, k = i2 - n * 1280;
    int rec = k / 320, u = k - rec * 320;
    float v = (n < 600 && u < 300) ? pW1[(size_t)n * 1200 + rec * 300 + u] : 0.f;
    W1h[i2] = (f16)v;
  }
}

// ---------------- MFMA input projection, F+B fused, scatter to XG2 ----------
__global__ __launch_bounds__(256) void k_projm(const float* __restrict__ A0,
        const float* __restrict__ A1, const int* __restrict__ g0,
        const int* __restrict__ g1, const f16* __restrict__ B16,
        const float* __restrict__ biasF, const float* __restrict__ biasB,
        f16* __restrict__ XG2, int Kreal, int Kpad, int lda) {
  __shared__ f16 As[128][40];
  __shared__ f16 Bs[128][40];
  int tid = threadIdx.x;
  int z = blockIdx.z;
  const float* A = z ? A1 : A0;
  const int* gather = z ? g1 : g0;
  int recbase = z * 2;
  int m0 = blockIdx.x * 128, n0 = blockIdx.y * 128;
  int w = tid >> 6, l = tid & 63, lo = l & 15, hi = l >> 4;
  int srow = tid >> 1, sk = (tid & 1) * 16;
  int sA_s = (m0 + srow) >> 5, sA_b = (m0 + srow) & 31;
  int itemA = sA_b * 64 + sA_s;
  const float* Arow = gather ? (A + (size_t)gather[itemA] * lda)
                             : (A + (size_t)itemA * lda);
  const f16* Brow = B16 + (size_t)(n0 + srow) * Kpad;
  f32x4 acc[2][8] = {};
  int nkt = Kpad >> 5;
  for (int kt = 0; kt < nkt; ++kt) {
    int k0 = kt * 32;
    #pragma unroll
    for (int q = 0; q < 16; q += 4) {
      int k = k0 + sk + q;
      if (k + 4 <= Kreal) {
        float4 v = *(const float4*)(Arow + k);
        As[srow][sk + q + 0] = (f16)v.x; As[srow][sk + q + 1] = (f16)v.y;
        As[srow][sk + q + 2] = (f16)v.z; As[srow][sk + q + 3] = (f16)v.w;
      } else {
        #pragma unroll
        for (int j = 0; j < 4; ++j)
          As[srow][sk + q + j] = (f16)((k + j < Kreal) ? Arow[k + j] : 0.f);
      }
    }
    *(f16x8*)(&Bs[srow][sk]) = *(const f16x8*)(Brow + k0 + sk);
    *(f16x8*)(&Bs[srow][sk + 8]) = *(const f16x8*)(Brow + k0 + sk + 8);
    __syncthreads();
    f16x8 Bf[8];
    #pragma unroll
    for (int nt = 0; nt < 8; ++nt)
      Bf[nt] = *(const f16x8*)(&Bs[nt * 16 + lo][hi * 8]);
    #pragma unroll
    for (int mt = 0; mt < 2; ++mt) {
      f16x8 Af = *(const f16x8*)(&As[w * 32 + mt * 16 + lo][hi * 8]);
      #pragma unroll
      for (int nt = 0; nt < 8; ++nt)
        acc[mt][nt] = __builtin_amdgcn_mfma_f32_16x16x32_f16(Af, Bf[nt], acc[mt][nt], 0, 0, 0);
    }
    __syncthreads();
  }
  int s = (m0 >> 5) + w;
  #pragma unroll
  for (int nt = 0; nt < 8; ++nt) {
    int n = n0 + nt * 16 + lo;
    if (n >= 2400) continue;
    int fb = n >= 1200;
    int nn = n - fb * 1200;
    int g = nn / 300;
    int u = nn - g * 300;
    int jb = u >> 5, ul = u & 31, nh = ul >> 4, lo2 = ul & 15;
    int rec = recbase + fb;
    int t = fb ? 63 - s : s;
    float bias = fb ? biasB[nn] : biasF[nn];
    size_t tbase = ((((size_t)(rec * 64 + t) * 10 + jb) * 4 + g) * 2 + nh) * 512
                   + (size_t)(hi * 16 + lo2) * 4;
    #pragma unroll
    for (int mt = 0; mt < 2; ++mt) {
      f16x4 hv;
      #pragma unroll
      for (int r = 0; r < 4; ++r) hv[r] = (f16)(acc[mt][nt][r] + bias);
      *(f16x4*)(XG2 + tbase + mt * 256) = hv;
    }
  }
}

// ---------------- distributed MFMA LSTM, batch-quarter chains ----------
// 160 blocks = 4 rec x 10 jb x 4 quarters (8 batch rows each). Per step:
// 5 KB stage, 10 MFMAs/wave (M=8 in M=16 tile; Hs rows 8..15 stay zero).
// Hbuf: [2 par][16 chain][8 b][160 u32]; chain = rec*4 + quarter.
__global__ __launch_bounds__(512, 1) void k_lstm10(
    const f16* __restrict__ Wh, const f16* __restrict__ XG2,
    unsigned int* __restrict__ Hbuf, unsigned int* __restrict__ O16u,
    unsigned int* __restrict__ flags) {
  int bid = blockIdx.x;
  int rec = bid / 40, rem = bid - rec * 40;
  int jb = rem >> 2, quar = rem & 3;
  int tid = threadIdx.x;
  int w = tid >> 6, l = tid & 63, lo = l & 15, hi = l >> 4;
  int g = w & 3, nh = w >> 2;

  __shared__ f16 Hs[16][328];
  __shared__ float zs[4][8][33];

  const f16* Wd = Wh + (size_t)(rec & 1) * 409600;
  int u_t = jb * 32 + nh * 16 + lo;
  f16x8 Bf[10];
  #pragma unroll
  for (int kt = 0; kt < 10; ++kt)
    Bf[kt] = *(const f16x8*)(Wd + ((size_t)g * 320 + u_t) * 320 + kt * 32 + hi * 8);

  // zero all of Hs once; rows 8..15 stay zero forever (pad rows => exact 0)
  for (int i = tid; i < 2624; i += 512) ((unsigned int*)Hs)[i] = 0u;
  __syncthreads();

  int cb = tid >> 5, cu = tid & 31;            // gate job: tid<256
  int u0c = jb * 32 + cu;
  float c0 = 0.f;
  int chain = rec * 4 + quar;
  unsigned int* fl = flags + chain * 160;
  int mtq = quar >> 1;
  int hiq = (quar & 1) * 2 + hi;               // valid for hi<2
  const f16* xgbase = XG2 + ((size_t)(rec * 64) * 10 + jb) * 4096
                      + ((size_t)(g * 2 + nh)) * 512 + mtq * 256
                      + (hiq * 16 + lo) * 4;
  bool ev = (cu & 1) == 0;
  bool upad = (u0c >= 300);
  bool hjob = (hi < 2);

  for (int t = 0; t < 64; ++t) {
    f16x4 xv = {};
    if (hjob) xv = *(const f16x4*)(xgbase + (size_t)t * 40960);

    if (t > 0) {
      if (tid < 10) {
        while (__hip_atomic_load(fl + tid * 16, __ATOMIC_RELAXED,
                                 __HIP_MEMORY_SCOPE_AGENT) < (unsigned)t) { }
      }
      __syncthreads();
    }
    // stage this quarter's h_t (5 KB): coherent u32 loads -> LDS rows 0..7
    {
      unsigned int* Hg = Hbuf + ((size_t)(t & 1) * 16 + chain) * 1280;
      #pragma unroll
      for (int q = 0; q < 3; ++q) {
        int idx = q * 512 + tid;
        if (idx < 1280) {
          unsigned int v = __hip_atomic_load(Hg + idx, __ATOMIC_RELAXED,
                                             __HIP_MEMORY_SCOPE_AGENT);
          int b = idx / 160, rm = idx - b * 160;
          *(unsigned int*)(&Hs[b][rm * 2]) = v;
        }
      }
    }
    __syncthreads();

    f32x4 acc = {};
    #pragma unroll
    for (int kt = 0; kt < 10; ++kt) {
      f16x8 Af = *(const f16x8*)(&Hs[lo][kt * 32 + hi * 8]);
      acc = __builtin_amdgcn_mfma_f32_16x16x32_f16(Af, Bf[kt], acc, 0, 0, 0);
    }
    if (hjob)
      #pragma unroll
      for (int r = 0; r < 4; ++r)
        zs[g][hi * 4 + r][nh * 16 + lo] = acc[r] + (float)xv[r];
    __syncthreads();

    int tt = (rec & 1) ? 63 - t : t;
    if (tid < 256) {
      float zi = zs[0][cb][cu], zf = zs[1][cb][cu];
      float zg = zs[2][cb][cu], zo = zs[3][cb][cu];
      float cn = fsig(zf) * c0 + fsig(zi) * ftanh(zg);
      float hn = fsig(zo) * ftanh(cn);
      c0 = cn;
      if (upad) hn = 0.f;
      union { f16 h; unsigned short s; } hb; hb.h = (f16)hn;
      int mine = (int)hb.s;
      int oth = __shfl_xor(mine, 1);
      unsigned int pk = ((unsigned)mine & 0xffffu) | ((unsigned)oth << 16);
      unsigned int* Hw = Hbuf + ((size_t)((t + 1) & 1) * 16 + chain) * 1280;
      if (ev)
        __hip_atomic_store(Hw + cb * 160 + jb * 16 + (cu >> 1), pk,
                           __ATOMIC_RELAXED, __HIP_MEMORY_SCOPE_AGENT);
      if (O16u && ev)
        O16u[((size_t)rec * 2048 + (quar * 8 + cb) * 64 + tt) * 160
             + jb * 16 + (cu >> 1)] = pk;
    }
    if (t < 63) {
      asm volatile("s_waitcnt vmcnt(0)" ::: "memory");   // stores acked at L3
      __syncthreads();
      if (tid == 0)
        __hip_atomic_store(fl + jb * 16, (unsigned)(t + 1), __ATOMIC_RELAXED,
                           __HIP_MEMORY_SCOPE_AGENT);
    }
  }
}

// ---------------- fused cosine (z=0) + pairwise match (z=1) ----------------
__global__ __launch_bounds__(256) void k_cospair(const f16* __restrict__ O16,
        const f16* __restrict__ WSQ, f16* __restrict__ COS16,
        float* __restrict__ RS, float* __restrict__ CS,
        float* __restrict__ V1, float* __restrict__ V2) {
  int b = blockIdx.x, d = blockIdx.y, which = blockIdx.z;
  __shared__ f16 As[64][328];
  __shared__ f16 Bs[64][328];
  __shared__ float ninv[2][64];
  __shared__ float scratch[6400];
  int tid = threadIdx.x;
  int w = tid >> 6, l = tid & 63, lo = l & 15, hi = l >> 4;
  int srow = tid >> 2, sseg = (tid & 3) * 80;
  int r2src = which ? 3 : 2 + d;
  const f16* ap = O16 + ((size_t)d * 2048 + b * 64 + srow) * 320 + sseg;
  const f16* bp = O16 + ((size_t)r2src * 2048 + b * 64 + srow) * 320 + sseg;
  #pragma unroll
  for (int q = 0; q < 80; q += 8) {
    *(f16x8*)(&As[srow][sseg + q]) = *(const f16x8*)(ap + q);
    *(f16x8*)(&Bs[srow][sseg + q]) = *(const f16x8*)(bp + q);
  }
  __syncthreads();
  if (tid < 128) {
    int wh = tid >> 6, row = tid & 63;
    float s = 0.f;
    for (int k = 0; k < 320; ++k) {
      float v = wh ? (float)Bs[row][k] : (float)As[row][k];
      s += v * v;
    }
    ninv[wh][row] = 1.f / sqrtf(s);
  }

  if (which == 0) {
    // ---- cosine + row/col sums ----
    float (*ctile)[68] = (float(*)[68])scratch;   // 64x68 = 4352 <= 6400
    f32x4 acc[4] = {};
    #pragma unroll
    for (int kt = 0; kt < 10; ++kt) {
      f16x8 Af = *(const f16x8*)(&As[w * 16 + lo][kt * 32 + hi * 8]);
      #pragma unroll
      for (int jt = 0; jt < 4; ++jt) {
        f16x8 Bfv = *(const f16x8*)(&Bs[jt * 16 + lo][kt * 32 + hi * 8]);
        acc[jt] = __builtin_amdgcn_mfma_f32_16x16x32_f16(Af, Bfv, acc[jt], 0, 0, 0);
      }
    }
    __syncthreads();
    float n1i[4];
    #pragma unroll
    for (int r = 0; r < 4; ++r) n1i[r] = ninv[0][w * 16 + hi * 4 + r];
    #pragma unroll
    for (int jt = 0; jt < 4; ++jt) {
      float n2j = ninv[1][jt * 16 + lo];
      #pragma unroll
      for (int r = 0; r < 4; ++r) {
        int i = w * 16 + hi * 4 + r, j = jt * 16 + lo;
        ctile[i][j] = acc[jt][r] * n1i[r] * n2j;
      }
    }
    __syncthreads();
    unsigned int* op = (unsigned int*)(COS16 + ((size_t)d * 32 + b) * 4096);
    for (int idx = tid; idx < 2048; idx += 256) {
      int i = idx >> 5, jc = idx & 31;
      union { f16x2 h; unsigned int u; } pk;
      pk.h[0] = (f16)ctile[i][jc * 2]; pk.h[1] = (f16)ctile[i][jc * 2 + 1];
      op[idx] = pk.u;
    }
    if (tid < 64) {
      float rs = 0.f;
      for (int k = 0; k < 64; ++k) rs += ctile[tid][k];
      RS[(d * 32 + b) * 64 + tid] = rs;
    } else if (tid < 128) {
      int j = tid - 64;
      float cs = 0.f;
      for (int k = 0; k < 64; ++k) cs += ctile[k][j];
      CS[(d * 32 + b) * 64 + j] = cs;
    }
  } else {
    // ---- pairwise match + fused max over i and j ----
    float* mjb = scratch;            // 64*20
    float* mir = scratch + 1280;     // 4*64*20
    __syncthreads();
    float n1i[4], n2i[4];
    #pragma unroll
    for (int r = 0; r < 4; ++r) n1i[r] = ninv[0][w * 16 + hi * 4 + r];
    #pragma unroll
    for (int jt = 0; jt < 4; ++jt) n2i[jt] = ninv[1][jt * 16 + lo];
    const f16* Wv = WSQ + (size_t)(4 + d) * 10240;
    for (int lq = 0; lq < 20; ++lq) {
      f32x4 acc[4] = {};
      #pragma unroll
      for (int kt = 0; kt < 10; ++kt) {
        f16x8 a = *(const f16x8*)(&As[w * 16 + lo][kt * 32 + hi * 8]);
        f16x8 wf = *(const f16x8*)(Wv + (size_t)lq * 320 + kt * 32 + hi * 8);
        f16x8 aw = a * wf;
        #pragma unroll
        for (int jt = 0; jt < 4; ++jt) {
          f16x8 bf = *(const f16x8*)(&Bs[jt * 16 + lo][kt * 32 + hi * 8]);
          acc[jt] = __builtin_amdgcn_mfma_f32_16x16x32_f16(aw, bf, acc[jt], 0, 0, 0);
        }
      }
      float mjr[4];
      #pragma unroll
      for (int r = 0; r < 4; ++r) {
        float m = acc[0][r] * n2i[0];
        #pragma unroll
        for (int jt = 1; jt < 4; ++jt) m = fmaxf(m, acc[jt][r] * n2i[jt]);
        mjr[r] = m;
      }
      #pragma unroll
      for (int off = 1; off < 16; off <<= 1)
        #pragma unroll
        for (int r = 0; r < 4; ++r) mjr[r] = fmaxf(mjr[r], __shfl_xor(mjr[r], off));
      if (lo == 0)
        #pragma unroll
        for (int r = 0; r < 4; ++r)
          mjb[(w * 16 + hi * 4 + r) * 20 + lq] = mjr[r] * n1i[r];
      float milo[4];
      #pragma unroll
      for (int jt = 0; jt < 4; ++jt) {
        float m = acc[jt][0] * n1i[0];
        #pragma unroll
        for (int r = 1; r < 4; ++r) m = fmaxf(m, acc[jt][r] * n1i[r]);
        float o16 = __shfl_xor(m, 16);
        float o32 = __shfl_xor(fmaxf(m, o16), 32);
        milo[jt] = fmaxf(fmaxf(m, o16), o32);
      }
      if (hi == 0)
        #pragma unroll
        for (int jt = 0; jt < 4; ++jt)
          mir[(w * 64 + jt * 16 + lo) * 20 + lq] = milo[jt] * n2i[jt];
    }
    __syncthreads();
    int offv0 = (d ? 100 : 20);
    for (int idx = tid; idx < 1280; idx += 256) {
      int i = idx / 20, lq = idx - i * 20;
      V1[((size_t)b * 64 + i) * 160 + offv0 + lq] = mjb[i * 20 + lq];
      float m = fmaxf(fmaxf(mir[(0 * 64 + i) * 20 + lq], mir[(1 * 64 + i) * 20 + lq]),
                      fmaxf(mir[(2 * 64 + i) * 20 + lq], mir[(3 * 64 + i) * 20 + lq]));
      V2[((size_t)b * 64 + i) * 160 + offv0 + lq] = m;
    }
  }
}

// ---------------- attention vectors: z=0 mean (MFMA), z=1 max ----------------
__global__ __launch_bounds__(256) void k_attn(const f16* __restrict__ O16,
        const f16* __restrict__ COS16, const float* __restrict__ RS,
        const float* __restrict__ CS, f16* __restrict__ MM16) {
  int b = blockIdx.x, v = blockIdx.y, mode = blockIdx.z;
  int d = v & 1, s2side = v >> 1;
  __shared__ f16 CT[64][72];
  __shared__ f16 ST[320][72];
  __shared__ f16 Cs[64][132];
  __shared__ unsigned int Ss[64][161];
  int tid = threadIdx.x;
  const unsigned int* Cp = (const unsigned int*)(COS16 + ((size_t)d * 32 + b) * 4096);
  int srcrec = s2side ? 0 : 2;
  const unsigned int* Sp = (const unsigned int*)(O16 + ((size_t)srcrec * 2048 + b * 64) * 320);

  if (mode == 0) {
    if (!s2side) {
      for (int idx = tid; idx < 2048; idx += 256) {
        int i = idx >> 5, jc = idx & 31;
        *(unsigned int*)(&CT[i][jc * 2]) = Cp[idx];
      }
    } else {
      for (int idx = tid; idx < 2048; idx += 256) {
        int i = idx >> 5, jc = idx & 31;
        union { unsigned int u; f16x2 h; } pk; pk.u = Cp[idx];
        CT[jc * 2][i] = pk.h[0];
        CT[jc * 2 + 1][i] = pk.h[1];
      }
    }
    for (int idx = tid; idx < 10240; idx += 256) {
      int k = idx / 160, c = idx - k * 160;
      union { unsigned int u; f16x2 h; } pk; pk.u = Sp[idx];
      ST[c * 2][k] = pk.h[0];
      ST[c * 2 + 1][k] = pk.h[1];
    }
    __syncthreads();
    int w = tid >> 6, l = tid & 63, lo = l & 15, hi = l >> 4;
    f32x4 acc[20] = {};
    #pragma unroll
    for (int kt = 0; kt < 2; ++kt) {
      f16x8 Af = *(const f16x8*)(&CT[w * 16 + lo][kt * 32 + hi * 8]);
      #pragma unroll
      for (int nt = 0; nt < 20; ++nt) {
        f16x8 Bfv = *(const f16x8*)(&ST[nt * 16 + lo][kt * 32 + hi * 8]);
        acc[nt] = __builtin_amdgcn_mfma_f32_16x16x32_f16(Af, Bfv, acc[nt], 0, 0, 0);
      }
    }
    const float* den = s2side ? CS : RS;
    float dv[4];
    #pragma unroll
    for (int r = 0; r < 4; ++r) dv[r] = den[(d * 32 + b) * 64 + w * 16 + hi * 4 + r];
    __syncthreads();
    f16 (*OT)[328] = (f16(*)[328])(&ST[0][0]);
    #pragma unroll
    for (int nt = 0; nt < 20; ++nt)
      #pragma unroll
      for (int r = 0; r < 4; ++r)
        OT[w * 16 + hi * 4 + r][nt * 16 + lo] = (f16)(acc[nt][r] / dv[r]);
    __syncthreads();
    unsigned int* Mp = (unsigned int*)(MM16 + ((size_t)v * 2048 + b * 64) * 320);
    for (int idx = tid; idx < 10240; idx += 256) {
      int m = idx / 160, c = idx - m * 160;
      union { f16x2 h; unsigned int u; } pk;
      pk.h[0] = OT[m][c * 2]; pk.h[1] = OT[m][c * 2 + 1];
      Mp[idx] = pk.u;
    }
  } else {
    for (int idx = tid; idx < 2048; idx += 256) {
      int i = idx >> 5, jc = idx & 31;
      *(unsigned int*)(&Cs[i][jc * 2]) = Cp[idx];
    }
    for (int idx = tid; idx < 10240; idx += 256) {
      int k = idx / 160, c = idx - k * 160;
      Ss[k][c] = Sp[idx];
    }
    __syncthreads();
    unsigned int* Mp = (unsigned int*)(MM16 + ((size_t)(4 + v) * 2048 + b * 64) * 320);
    for (int idx = tid; idx < 10240; idx += 256) {
      int r = idx / 160, c = idx - r * 160;
      f16 cv = s2side ? Cs[0][r] : Cs[r][0];
      union { unsigned int u; f16x2 h; } sv; sv.u = Ss[0][c];
      f16x2 cc; cc[0] = cv; cc[1] = cv;
      f16x2 mx = cc * sv.h;
      for (int inner = 1; inner < 64; ++inner) {
        f16 cv2 = s2side ? Cs[inner][r] : Cs[r][inner];
        sv.u = Ss[inner][c];
        f16x2 c2; c2[0] = cv2; c2[1] = cv2;
        f16x2 p = c2 * sv.h;
        mx[0] = p[0] > mx[0] ? p[0] : mx[0];
        mx[1] = p[1] > mx[1] ? p[1] : mx[1];
      }
      union { f16x2 h; unsigned int u; } o; o.h = mx;
      Mp[idx] = o.u;
    }
  }
}

// ---------------- MFMA full-match (12 variants), f16 inputs ----------------
__global__ __launch_bounds__(256) void k_fmm(const f16* __restrict__ O16,
        const f16* __restrict__ MM16, const f16* __restrict__ WSQ,
        float* __restrict__ V1, float* __restrict__ V2) {
  int ib = blockIdx.x, var = blockIdx.y;
  int tid = threadIdx.x;
  int w = tid >> 6, l = tid & 63, lo = l & 15, hi = l >> 4;
  int mt = w & 1, nt = w >> 1;
  __shared__ f16 Vs1[32][328];
  __shared__ f16 Vs2[32][328];
  __shared__ float zs[3][32][21];

  const f16* s1f = O16;
  const f16* s1b = O16 + (size_t)2048 * 320;
  const f16* s2f = O16 + (size_t)2 * 2048 * 320;
  const f16* s2b = O16 + (size_t)3 * 2048 * 320;
  const f16 *v1b, *v2b;
  int v2fix = 0, v2off = 0, wi, co;
  float* outbase;
  switch (var) {
    case 0:  v1b = s1f; v2b = s2f; v2fix = 1; v2off = 63; wi = 0; outbase = V1; co = 0;   break;
    case 1:  v1b = s1f; v2b = MM16 + (size_t)0 * 655360; wi = 2; outbase = V1; co = 40; break;
    case 2:  v1b = s1f; v2b = MM16 + (size_t)4 * 655360; wi = 3; outbase = V1; co = 60; break;
    case 3:  v1b = s1b; v2b = s2b; v2fix = 1; v2off = 0; wi = 1; outbase = V1; co = 80; break;
    case 4:  v1b = s1b; v2b = MM16 + (size_t)1 * 655360; wi = 2; outbase = V1; co = 120; break;
    case 5:  v1b = s1b; v2b = MM16 + (size_t)5 * 655360; wi = 3; outbase = V1; co = 140; break;
    case 6:  v1b = s2f; v2b = s1f; v2fix = 1; v2off = 63; wi = 0; outbase = V2; co = 0; break;
    case 7:  v1b = s2f; v2b = MM16 + (size_t)2 * 655360; wi = 2; outbase = V2; co = 40; break;
    case 8:  v1b = s2f; v2b = MM16 + (size_t)6 * 655360; wi = 3; outbase = V2; co = 60; break;
    case 9:  v1b = s2b; v2b = s1b; v2fix = 1; v2off = 0; wi = 1; outbase = V2; co = 80; break;
    case 10: v1b = s2b; v2b = MM16 + (size_t)3 * 655360; wi = 2; outbase = V2; co = 120; break;
    default: v1b = s2b; v2b = MM16 + (size_t)7 * 655360; wi = 3; outbase = V2; co = 140; break;
  }
  int srow = tid >> 3;
  int m1 = ib * 32 + srow;
  int m2 = v2fix ? (m1 & ~63) + v2off : m1;
  const unsigned int* r1 = (const unsigned int*)(v1b + (size_t)m1 * 320);
  const unsigned int* r2 = (const unsigned int*)(v2b + (size_t)m2 * 320);
  #pragma unroll
  for (int q = 0; q < 20; ++q) {
    int c = (tid & 7) + q * 8;
    *(unsigned int*)(&Vs1[srow][c * 2]) = r1[c];
    *(unsigned int*)(&Vs2[srow][c * 2]) = r2[c];
  }
  __syncthreads();

  const f16* Wv = WSQ + (size_t)wi * 10240;
  f32x4 acc[3] = {};
  #pragma unroll
  for (int kt = 0; kt < 10; ++kt) {
    f16x8 a1 = *(const f16x8*)(&Vs1[mt * 16 + lo][kt * 32 + hi * 8]);
    f16x8 a2 = *(const f16x8*)(&Vs2[mt * 16 + lo][kt * 32 + hi * 8]);
    f16x8 bf = *(const f16x8*)(Wv + ((size_t)(nt * 16 + lo)) * 320 + kt * 32 + hi * 8);
    acc[0] = __builtin_amdgcn_mfma_f32_16x16x32_f16(a1 * a2, bf, acc[0], 0, 0, 0);
    acc[1] = __builtin_amdgcn_mfma_f32_16x16x32_f16(a1 * a1, bf, acc[1], 0, 0, 0);
    acc[2] = __builtin_amdgcn_mfma_f32_16x16x32_f16(a2 * a2, bf, acc[2], 0, 0, 0);
  }
  #pragma unroll
  for (int pt = 0; pt < 3; ++pt)
    #pragma unroll
    for (int r = 0; r < 4; ++r) {
      int item = mt * 16 + hi * 4 + r, lcol = nt * 16 + lo;
      if (lcol < 20) zs[pt][item][lcol] = acc[pt][r];
    }
  __syncthreads();
  for (int idx = tid; idx < 640; idx += 256) {
    int item = idx / 20, lcol = idx - item * 20;
    float sn = zs[0][item][lcol], sa = zs[1][item][lcol], sb = zs[2][item][lcol];
    float o = sn / (fmaxf(sqrtf(sa), EPSF) * fmaxf(sqrtf(sb), EPSF));
    outbase[(size_t)(ib * 32 + item) * 160 + co + lcol] = o;
  }
}

// ---------------- MFMA hidden layer: XS = tanh(Hfin . W1h^T + b1) ----------
// Hfin = Hbuf parity-0: [16 chain][8 b][160 u32], chain = rec*4 + (b>>3).
__global__ __launch_bounds__(256) void k_mlpA(const unsigned int* __restrict__ Hp,
        const f16* __restrict__ W1h, const float* __restrict__ b1,
        float* __restrict__ XS) {
  __shared__ f16 Amat[32][1288];
  int tid = threadIdx.x;
  int n0 = blockIdx.x * 128;
  for (int i = tid; i < 20480; i += 256) {
    int rec = i / 5120, rem = i - rec * 5120;
    int b = rem / 160, uc = rem - b * 160;
    unsigned int v = Hp[(size_t)(rec * 4 + (b >> 3)) * 1280 + (b & 7) * 160 + uc];
    *(unsigned int*)(&Amat[b][rec * 320 + uc * 2]) = v;
  }
  __syncthreads();
  int w = tid >> 6, l = tid & 63, lo = l & 15, hi = l >> 4;
  f32x4 acc[2][2] = {};
  for (int kt = 0; kt < 40; ++kt) {
    f16x8 Bf[2];
    #pragma unroll
    for (int nt = 0; nt < 2; ++nt) {
      int n = n0 + (w * 2 + nt) * 16 + lo;
      Bf[nt] = *(const f16x8*)(W1h + (size_t)n * 1280 + kt * 32 + hi * 8);
    }
    #pragma unroll
    for (int mt = 0; mt < 2; ++mt) {
      f16x8 Af = *(const f16x8*)(&Amat[mt * 16 + lo][kt * 32 + hi * 8]);
      #pragma unroll
      for (int nt = 0; nt < 2; ++nt)
        acc[mt][nt] = __builtin_amdgcn_mfma_f32_16x16x32_f16(Af, Bf[nt], acc[mt][nt], 0, 0, 0);
    }
  }
  #pragma unroll
  for (int mt = 0; mt < 2; ++mt)
    #pragma unroll
    for (int nt = 0; nt < 2; ++nt) {
      int n = n0 + (w * 2 + nt) * 16 + lo;
      if (n < 600) {
        float bias = b1[n];
        #pragma unroll
        for (int r = 0; r < 4; ++r) {
          int b = mt * 16 + hi * 4 + r;
          XS[(size_t)b * 600 + n] = ftanh(acc[mt][nt][r] + bias);
        }
      }
    }
}

// ---------------- logits + log_softmax ----------------
__global__ __launch_bounds__(64) void k_mlpB(const float* __restrict__ XS,
        const float* __restrict__ W2, const float* __restrict__ b2,
        float* __restrict__ out) {
  int b = blockIdx.x, lane = threadIdx.x;
  float p0 = 0.f, p1 = 0.f;
  for (int k = lane; k < 600; k += 64) {
    float xv = XS[(size_t)b * 600 + k];
    p0 += xv * W2[k];
    p1 += xv * W2[600 + k];
  }
  #pragma unroll
  for (int off = 32; off; off >>= 1) { p0 += __shfl_xor(p0, off); p1 += __shfl_xor(p1, off); }
  if (lane == 0) {
    float l0 = p0 + b2[0], l1 = p1 + b2[1];
    float m = fmaxf(l0, l1);
    float lse = m + logf(expf(l0 - m) + expf(l1 - m));
    out[b * 2 + 0] = l0 - lse;
    out[b * 2 + 1] = l1 - lse;
  }
}

extern "C" void kernel_launch(void* const* d_in, const int* in_sizes, int n_in,
                              void* d_out, int out_size, void* d_ws, size_t ws_size,
                              hipStream_t stream) {
  (void)in_sizes; (void)out_size;
  if (n_in < 25) return;
  const float* emb    = (const float*)d_in[0];
  const float* cWihF  = (const float*)d_in[1];
  const float* cWhhF  = (const float*)d_in[2];
  const float* cbF    = (const float*)d_in[3];
  const float* cWihB  = (const float*)d_in[4];
  const float* cWhhB  = (const float*)d_in[5];
  const float* cbB    = (const float*)d_in[6];
  const float* aWihF  = (const float*)d_in[7];
  const float* aWhhF  = (const float*)d_in[8];
  const float* abF    = (const float*)d_in[9];
  const float* aWihB  = (const float*)d_in[10];
  const float* aWhhB  = (const float*)d_in[11];
  const float* abB    = (const float*)d_in[12];
  const float* WfullF = (const float*)d_in[13];
  const float* WfullB = (const float*)d_in[14];
  const float* WmaxpF = (const float*)d_in[15];
  const float* WmaxpB = (const float*)d_in[16];
  const float* WattnF = (const float*)d_in[17];
  const float* WmaxaF = (const float*)d_in[18];
  const float* pW1    = (const float*)d_in[19];
  const float* pb1    = (const float*)d_in[20];
  const float* pW2    = (const float*)d_in[21];
  const float* pb2    = (const float*)d_in[22];
  const int*   sa     = (const int*)d_in[23];
  const int*   sb     = (const int*)d_in[24];
  float* out = (float*)d_out;
  float* ws = (float*)d_ws;

  // ---- workspace layout (float offsets) ----
  if (ws_size < (size_t)9297664 * 4) return;
  f16*   W1h  = (f16*)(ws + 0);                //  409600 fl
  float* XS   = ws + 409600;                   //   19200
  f16*   B16c = (f16*)(ws + 428800);           //  389120 fl
  f16*   B16a = (f16*)(ws + 817920);           //  194560 fl
  f16*   Wh16 = (f16*)(ws + 1012480);          //  819200 fl
  f16*   WSQ  = (f16*)(ws + 1831680);          //   30720 fl
  unsigned int* HbufA  = (unsigned int*)(ws + 1862400);  // 40960 u32
  unsigned int* flagsA = (unsigned int*)(ws + 1903360);  //  2560 u32
  unsigned int* HbufB  = (unsigned int*)(ws + 1905920);  // 40960 u32
  unsigned int* flagsB = (unsigned int*)(ws + 1946880);  //  2560 u32
  f16*   COS16 = (f16*)(ws + 1949440);         //  131072 fl
  float* RS   = ws + 2080512;                  //    4096
  float* CS   = ws + 2084608;                  //    4096
  float* V1   = ws + 2088704;                  //  327680
  float* V2   = ws + 2416384;                  //  327680
  unsigned int* O16u = (unsigned int*)(ws + 2744064);   // 1310720 fl
  f16*   O16  = (f16*)O16u;
  f16*   XG2  = (f16*)(ws + 4054784);          // 5242880 fl
  f16*   MM16 = XG2;                           //  alias (2621440 fl needed)

  f16* WhCtx = Wh16;
  f16* WhAgg = Wh16 + (size_t)2 * 409600;

  // ---- both H/flag regions zeroed up front (one memset, off critical path) ----
  hipMemsetAsync(HbufA, 0, 348160, stream);    // HbufA+flagsA+HbufB+flagsB

  // ---- unified weight prep ----
  k_prep<<<14400, 256, 0, stream>>>(cWhhF, cWhhB, aWhhF, aWhhB,
      cWihF, cWihB, aWihF, aWihB,
      WfullF, WfullB, WattnF, WmaxaF, WmaxpF, WmaxpB, pW1,
      Wh16, B16c, B16a, WSQ, W1h);

  // ---- context BiLSTM ----
  k_projm<<<dim3(16, 19, 2), 256, 0, stream>>>(emb, emb, sa, sb, B16c, cbF, cbB, XG2, 300, 320, 300);
  k_lstm10<<<160, 512, 0, stream>>>(WhCtx, XG2, HbufA, O16u, flagsA);

  // ---- matching ----
  k_cospair<<<dim3(32, 2, 2), 256, 0, stream>>>(O16, WSQ, COS16, RS, CS, V1, V2);
  k_attn<<<dim3(32, 4, 2), 256, 0, stream>>>(O16, COS16, RS, CS, MM16);
  k_fmm<<<dim3(64, 12), 256, 0, stream>>>(O16, MM16, WSQ, V1, V2);

  // ---- aggregation BiLSTM ----
  k_projm<<<dim3(16, 19, 2), 256, 0, stream>>>(V1, V2, nullptr, nullptr, B16a, abF, abB, XG2, 160, 160, 160);
  k_lstm10<<<160, 512, 0, stream>>>(WhAgg, XG2, HbufB, nullptr, flagsB);

  // ---- prediction head ----
  k_mlpA<<<5, 256, 0, stream>>>(HbufB, W1h, pb1, XS);
  k_mlpB<<<32, 64, 0, stream>>>(XS, pW2, pb2, out);
}

// Round 15
// 527.251 us; speedup vs baseline: 1.6008x; 1.0147x over previous
//
#include <hip/hip_runtime.h>
#include <math.h>

#define B_ 32
#define S_ 64
#define H_ 300
#define M_ 2048          // B*S
#define EPSF 1e-8f

typedef _Float16 f16;
typedef _Float16 f16x2 __attribute__((ext_vector_type(2)));
typedef _Float16 f16x4 __attribute__((ext_vector_type(4)));
typedef _Float16 f16x8 __attribute__((ext_vector_type(8)));
typedef float f32x4 __attribute__((ext_vector_type(4)));

__device__ __forceinline__ float fsig(float x) {
  return __builtin_amdgcn_rcpf(1.f + __expf(-x));
}
__device__ __forceinline__ float ftanh(float x) {
  return 1.f - 2.f * __builtin_amdgcn_rcpf(__expf(2.f * x) + 1.f);
}

// ---------------- unified weight prep (all conversions in one launch) ------
__global__ __launch_bounds__(256) void k_prep(
        const float* __restrict__ cWhhF, const float* __restrict__ cWhhB,
        const float* __restrict__ aWhhF, const float* __restrict__ aWhhB,
        const float* __restrict__ cWihF, const float* __restrict__ cWihB,
        const float* __restrict__ aWihF, const float* __restrict__ aWihB,
        const float* __restrict__ W0, const float* __restrict__ W1,
        const float* __restrict__ W2, const float* __restrict__ W3,
        const float* __restrict__ W4, const float* __restrict__ W5,
        const float* __restrict__ pW1,
        f16* __restrict__ Wh16, f16* __restrict__ B16c, f16* __restrict__ B16a,
        f16* __restrict__ WSQ, f16* __restrict__ W1h) {
  int idx = blockIdx.x * 256 + threadIdx.x;
  if (idx < 1638400) {
    int wsel = idx / 409600, rem0 = idx - wsel * 409600;
    const float* W = wsel == 0 ? cWhhF : wsel == 1 ? cWhhB : wsel == 2 ? aWhhF : aWhhB;
    int g = rem0 / 102400, rem = rem0 - g * 102400;
    int u = rem / 320, k = rem - u * 320;
    float v = (u < 300 && k < 300) ? W[((size_t)g * 300 + u) * 300 + k] : 0.f;
    Wh16[idx] = (f16)v;
  } else if (idx < 2416640) {
    int i2 = idx - 1638400;
    int n = i2 / 320, k = i2 - n * 320;
    float v = 0.f;
    if (n < 2400 && k < 300) {
      int fb = n >= 1200;
      int nn = n - fb * 1200;
      v = (fb ? cWihB : cWihF)[(size_t)nn * 300 + k];
    }
    B16c[i2] = (f16)v;
  } else if (idx < 2805760) {
    int i2 = idx - 2416640;
    int n = i2 / 160, k = i2 - n * 160;
    float v = 0.f;
    if (n < 2400) {
      int fb = n >= 1200;
      int nn = n - fb * 1200;
      v = (fb ? aWihB : aWihF)[(size_t)nn * 160 + k];
    }
    B16a[i2] = (f16)v;
  } else if (idx < 2867200) {
    int i2 = idx - 2805760;
    int wi = i2 / 10240, rem = i2 - wi * 10240;
    int r = rem / 320, k = rem - r * 320;
    float v = 0.f;
    if (r < 20 && k < 300) {
      const float* W = wi == 0 ? W0 : wi == 1 ? W1 : wi == 2 ? W2
                     : wi == 3 ? W3 : wi == 4 ? W4 : W5;
      float w = W[(size_t)r * 300 + k];
      v = w * w;
    }
    WSQ[i2] = (f16)v;
  } else if (idx < 3686400) {
    int i2 = idx - 2867200;
    int n = i2 / 1280, k = i2 - n * 1280;
    int rec = k / 320, u = k - rec * 320;
    float v = (n < 600 && u < 300) ? pW1[(size_t)n * 1200 + rec * 300 + u] : 0.f;
    W1h[i2] = (f16)v;
  }
}

// ---------------- MFMA input projection, F+B fused, scatter to XG2 ----------
__global__ __launch_bounds__(256) void k_projm(const float* __restrict__ A0,
        const float* __restrict__ A1, const int* __restrict__ g0,
        const int* __restrict__ g1, const f16* __restrict__ B16,
        const float* __restrict__ biasF, const float* __restrict__ biasB,
        f16* __restrict__ XG2, int Kreal, int Kpad, int lda) {
  __shared__ f16 As[128][40];
  __shared__ f16 Bs[128][40];
  int tid = threadIdx.x;
  int z = blockIdx.z;
  const float* A = z ? A1 : A0;
  const int* gather = z ? g1 : g0;
  int recbase = z * 2;
  int m0 = blockIdx.x * 128, n0 = blockIdx.y * 128;
  int w = tid >> 6, l = tid & 63, lo = l & 15, hi = l >> 4;
  int srow = tid >> 1, sk = (tid & 1) * 16;
  int sA_s = (m0 + srow) >> 5, sA_b = (m0 + srow) & 31;
  int itemA = sA_b * 64 + sA_s;
  const float* Arow = gather ? (A + (size_t)gather[itemA] * lda)
                             : (A + (size_t)itemA * lda);
  const f16* Brow = B16 + (size_t)(n0 + srow) * Kpad;
  f32x4 acc[2][8] = {};
  int nkt = Kpad >> 5;
  for (int kt = 0; kt < nkt; ++kt) {
    int k0 = kt * 32;
    #pragma unroll
    for (int q = 0; q < 16; q += 4) {
      int k = k0 + sk + q;
      if (k + 4 <= Kreal) {
        float4 v = *(const float4*)(Arow + k);
        As[srow][sk + q + 0] = (f16)v.x; As[srow][sk + q + 1] = (f16)v.y;
        As[srow][sk + q + 2] = (f16)v.z; As[srow][sk + q + 3] = (f16)v.w;
      } else {
        #pragma unroll
        for (int j = 0; j < 4; ++j)
          As[srow][sk + q + j] = (f16)((k + j < Kreal) ? Arow[k + j] : 0.f);
      }
    }
    *(f16x8*)(&Bs[srow][sk]) = *(const f16x8*)(Brow + k0 + sk);
    *(f16x8*)(&Bs[srow][sk + 8]) = *(const f16x8*)(Brow + k0 + sk + 8);
    __syncthreads();
    f16x8 Bf[8];
    #pragma unroll
    for (int nt = 0; nt < 8; ++nt)
      Bf[nt] = *(const f16x8*)(&Bs[nt * 16 + lo][hi * 8]);
    #pragma unroll
    for (int mt = 0; mt < 2; ++mt) {
      f16x8 Af = *(const f16x8*)(&As[w * 32 + mt * 16 + lo][hi * 8]);
      #pragma unroll
      for (int nt = 0; nt < 8; ++nt)
        acc[mt][nt] = __builtin_amdgcn_mfma_f32_16x16x32_f16(Af, Bf[nt], acc[mt][nt], 0, 0, 0);
    }
    __syncthreads();
  }
  int s = (m0 >> 5) + w;
  #pragma unroll
  for (int nt = 0; nt < 8; ++nt) {
    int n = n0 + nt * 16 + lo;
    if (n >= 2400) continue;
    int fb = n >= 1200;
    int nn = n - fb * 1200;
    int g = nn / 300;
    int u = nn - g * 300;
    int jb = u >> 5, ul = u & 31, nh = ul >> 4, lo2 = ul & 15;
    int rec = recbase + fb;
    int t = fb ? 63 - s : s;
    float bias = fb ? biasB[nn] : biasF[nn];
    size_t tbase = ((((size_t)(rec * 64 + t) * 10 + jb) * 4 + g) * 2 + nh) * 512
                   + (size_t)(hi * 16 + lo2) * 4;
    #pragma unroll
    for (int mt = 0; mt < 2; ++mt) {
      f16x4 hv;
      #pragma unroll
      for (int r = 0; r < 4; ++r) hv[r] = (f16)(acc[mt][nt][r] + bias);
      *(f16x4*)(XG2 + tbase + mt * 256) = hv;
    }
  }
}

// ---------------- distributed MFMA LSTM, batch-eighth chains ----------
// 320 blocks = 4 rec x 10 jb x 8 eighths (4 batch rows each). Per step:
// 2.5 KB stage, 10 MFMAs/wave (M=4 in M=16 tile; Hs rows 4..15 stay zero).
// Hbuf: [2 par][32 chain][4 b][160 u32]; chain = rec*8 + eighth.
__global__ __launch_bounds__(512, 1) void k_lstm11(
    const f16* __restrict__ Wh, const f16* __restrict__ XG2,
    unsigned int* __restrict__ Hbuf, unsigned int* __restrict__ O16u,
    unsigned int* __restrict__ flags) {
  int bid = blockIdx.x;
  int rec = bid / 80, rem = bid - rec * 80;
  int jb = rem >> 3, eig = rem & 7;
  int tid = threadIdx.x;
  int w = tid >> 6, l = tid & 63, lo = l & 15, hi = l >> 4;
  int g = w & 3, nh = w >> 2;

  __shared__ f16 Hs[16][328];
  __shared__ float zs[4][4][33];

  const f16* Wd = Wh + (size_t)(rec & 1) * 409600;
  int u_t = jb * 32 + nh * 16 + lo;
  f16x8 Bf[10];
  #pragma unroll
  for (int kt = 0; kt < 10; ++kt)
    Bf[kt] = *(const f16x8*)(Wd + ((size_t)g * 320 + u_t) * 320 + kt * 32 + hi * 8);

  // zero all of Hs once; rows 4..15 stay zero forever (pad rows => exact 0)
  for (int i = tid; i < 2624; i += 512) ((unsigned int*)Hs)[i] = 0u;
  __syncthreads();

  int cb = tid >> 5, cu = tid & 31;            // gate job: tid<128
  int u0c = jb * 32 + cu;
  float c0 = 0.f;
  int chain = rec * 8 + eig;
  unsigned int* fl = flags + chain * 160;
  int mtq = eig >> 2;
  int hiq = eig & 3;
  const f16* xgbase = XG2 + ((size_t)(rec * 64) * 10 + jb) * 4096
                      + ((size_t)(g * 2 + nh)) * 512 + mtq * 256
                      + (hiq * 16 + lo) * 4;
  bool ev = (cu & 1) == 0;
  bool upad = (u0c >= 300);
  bool hjob = (hi == 0);

  for (int t = 0; t < 64; ++t) {
    f16x4 xv = {};
    if (hjob) xv = *(const f16x4*)(xgbase + (size_t)t * 40960);

    if (t > 0) {
      if (tid < 10) {
        while (__hip_atomic_load(fl + tid * 16, __ATOMIC_RELAXED,
                                 __HIP_MEMORY_SCOPE_AGENT) < (unsigned)t) { }
      }
      __syncthreads();
    }
    // stage this eighth's h_t (2.5 KB): coherent u32 loads -> LDS rows 0..3
    {
      unsigned int* Hg = Hbuf + ((size_t)(t & 1) * 32 + chain) * 640;
      #pragma unroll
      for (int q = 0; q < 2; ++q) {
        int idx = q * 512 + tid;
        if (idx < 640) {
          unsigned int v = __hip_atomic_load(Hg + idx, __ATOMIC_RELAXED,
                                             __HIP_MEMORY_SCOPE_AGENT);
          int b = idx / 160, rm = idx - b * 160;
          *(unsigned int*)(&Hs[b][rm * 2]) = v;
        }
      }
    }
    __syncthreads();

    f32x4 acc = {};
    #pragma unroll
    for (int kt = 0; kt < 10; ++kt) {
      f16x8 Af = *(const f16x8*)(&Hs[lo][kt * 32 + hi * 8]);
      acc = __builtin_amdgcn_mfma_f32_16x16x32_f16(Af, Bf[kt], acc, 0, 0, 0);
    }
    if (hjob)
      #pragma unroll
      for (int r = 0; r < 4; ++r)
        zs[g][r][nh * 16 + lo] = acc[r] + (float)xv[r];
    __syncthreads();

    int tt = (rec & 1) ? 63 - t : t;
    if (tid < 128) {
      float zi = zs[0][cb][cu], zf = zs[1][cb][cu];
      float zg = zs[2][cb][cu], zo = zs[3][cb][cu];
      float cn = fsig(zf) * c0 + fsig(zi) * ftanh(zg);
      float hn = fsig(zo) * ftanh(cn);
      c0 = cn;
      if (upad) hn = 0.f;
      union { f16 h; unsigned short s; } hb; hb.h = (f16)hn;
      int mine = (int)hb.s;
      int oth = __shfl_xor(mine, 1);
      unsigned int pk = ((unsigned)mine & 0xffffu) | ((unsigned)oth << 16);
      unsigned int* Hw = Hbuf + ((size_t)((t + 1) & 1) * 32 + chain) * 640;
      if (ev)
        __hip_atomic_store(Hw + cb * 160 + jb * 16 + (cu >> 1), pk,
                           __ATOMIC_RELAXED, __HIP_MEMORY_SCOPE_AGENT);
      if (O16u && ev)
        O16u[((size_t)rec * 2048 + (eig * 4 + cb) * 64 + tt) * 160
             + jb * 16 + (cu >> 1)] = pk;
    }
    if (t < 63) {
      asm volatile("s_waitcnt vmcnt(0)" ::: "memory");   // stores acked at L3
      __syncthreads();
      if (tid == 0)
        __hip_atomic_store(fl + jb * 16, (unsigned)(t + 1), __ATOMIC_RELAXED,
                           __HIP_MEMORY_SCOPE_AGENT);
    }
  }
}

// ---------------- fused cosine (z=0) + pairwise match (z=1) ----------------
__global__ __launch_bounds__(256) void k_cospair(const f16* __restrict__ O16,
        const f16* __restrict__ WSQ, f16* __restrict__ COS16,
        float* __restrict__ RS, float* __restrict__ CS,
        float* __restrict__ V1, float* __restrict__ V2) {
  int b = blockIdx.x, d = blockIdx.y, which = blockIdx.z;
  __shared__ f16 As[64][328];
  __shared__ f16 Bs[64][328];
  __shared__ float ninv[2][64];
  __shared__ float scratch[6400];
  int tid = threadIdx.x;
  int w = tid >> 6, l = tid & 63, lo = l & 15, hi = l >> 4;
  int srow = tid >> 2, sseg = (tid & 3) * 80;
  int r2src = which ? 3 : 2 + d;
  const f16* ap = O16 + ((size_t)d * 2048 + b * 64 + srow) * 320 + sseg;
  const f16* bp = O16 + ((size_t)r2src * 2048 + b * 64 + srow) * 320 + sseg;
  #pragma unroll
  for (int q = 0; q < 80; q += 8) {
    *(f16x8*)(&As[srow][sseg + q]) = *(const f16x8*)(ap + q);
    *(f16x8*)(&Bs[srow][sseg + q]) = *(const f16x8*)(bp + q);
  }
  __syncthreads();
  if (tid < 128) {
    int wh = tid >> 6, row = tid & 63;
    float s = 0.f;
    for (int k = 0; k < 320; ++k) {
      float v = wh ? (float)Bs[row][k] : (float)As[row][k];
      s += v * v;
    }
    ninv[wh][row] = 1.f / sqrtf(s);
  }

  if (which == 0) {
    float (*ctile)[68] = (float(*)[68])scratch;
    f32x4 acc[4] = {};
    #pragma unroll
    for (int kt = 0; kt < 10; ++kt) {
      f16x8 Af = *(const f16x8*)(&As[w * 16 + lo][kt * 32 + hi * 8]);
      #pragma unroll
      for (int jt = 0; jt < 4; ++jt) {
        f16x8 Bfv = *(const f16x8*)(&Bs[jt * 16 + lo][kt * 32 + hi * 8]);
        acc[jt] = __builtin_amdgcn_mfma_f32_16x16x32_f16(Af, Bfv, acc[jt], 0, 0, 0);
      }
    }
    __syncthreads();
    float n1i[4];
    #pragma unroll
    for (int r = 0; r < 4; ++r) n1i[r] = ninv[0][w * 16 + hi * 4 + r];
    #pragma unroll
    for (int jt = 0; jt < 4; ++jt) {
      float n2j = ninv[1][jt * 16 + lo];
      #pragma unroll
      for (int r = 0; r < 4; ++r) {
        int i = w * 16 + hi * 4 + r, j = jt * 16 + lo;
        ctile[i][j] = acc[jt][r] * n1i[r] * n2j;
      }
    }
    __syncthreads();
    unsigned int* op = (unsigned int*)(COS16 + ((size_t)d * 32 + b) * 4096);
    for (int idx = tid; idx < 2048; idx += 256) {
      int i = idx >> 5, jc = idx & 31;
      union { f16x2 h; unsigned int u; } pk;
      pk.h[0] = (f16)ctile[i][jc * 2]; pk.h[1] = (f16)ctile[i][jc * 2 + 1];
      op[idx] = pk.u;
    }
    if (tid < 64) {
      float rs = 0.f;
      for (int k = 0; k < 64; ++k) rs += ctile[tid][k];
      RS[(d * 32 + b) * 64 + tid] = rs;
    } else if (tid < 128) {
      int j = tid - 64;
      float cs = 0.f;
      for (int k = 0; k < 64; ++k) cs += ctile[k][j];
      CS[(d * 32 + b) * 64 + j] = cs;
    }
  } else {
    float* mjb = scratch;
    float* mir = scratch + 1280;
    __syncthreads();
    float n1i[4], n2i[4];
    #pragma unroll
    for (int r = 0; r < 4; ++r) n1i[r] = ninv[0][w * 16 + hi * 4 + r];
    #pragma unroll
    for (int jt = 0; jt < 4; ++jt) n2i[jt] = ninv[1][jt * 16 + lo];
    const f16* Wv = WSQ + (size_t)(4 + d) * 10240;
    for (int lq = 0; lq < 20; ++lq) {
      f32x4 acc[4] = {};
      #pragma unroll
      for (int kt = 0; kt < 10; ++kt) {
        f16x8 a = *(const f16x8*)(&As[w * 16 + lo][kt * 32 + hi * 8]);
        f16x8 wf = *(const f16x8*)(Wv + (size_t)lq * 320 + kt * 32 + hi * 8);
        f16x8 aw = a * wf;
        #pragma unroll
        for (int jt = 0; jt < 4; ++jt) {
          f16x8 bf = *(const f16x8*)(&Bs[jt * 16 + lo][kt * 32 + hi * 8]);
          acc[jt] = __builtin_amdgcn_mfma_f32_16x16x32_f16(aw, bf, acc[jt], 0, 0, 0);
        }
      }
      float mjr[4];
      #pragma unroll
      for (int r = 0; r < 4; ++r) {
        float m = acc[0][r] * n2i[0];
        #pragma unroll
        for (int jt = 1; jt < 4; ++jt) m = fmaxf(m, acc[jt][r] * n2i[jt]);
        mjr[r] = m;
      }
      #pragma unroll
      for (int off = 1; off < 16; off <<= 1)
        #pragma unroll
        for (int r = 0; r < 4; ++r) mjr[r] = fmaxf(mjr[r], __shfl_xor(mjr[r], off));
      if (lo == 0)
        #pragma unroll
        for (int r = 0; r < 4; ++r)
          mjb[(w * 16 + hi * 4 + r) * 20 + lq] = mjr[r] * n1i[r];
      float milo[4];
      #pragma unroll
      for (int jt = 0; jt < 4; ++jt) {
        float m = acc[jt][0] * n1i[0];
        #pragma unroll
        for (int r = 1; r < 4; ++r) m = fmaxf(m, acc[jt][r] * n1i[r]);
        float o16 = __shfl_xor(m, 16);
        float o32 = __shfl_xor(fmaxf(m, o16), 32);
        milo[jt] = fmaxf(fmaxf(m, o16), o32);
      }
      if (hi == 0)
        #pragma unroll
        for (int jt = 0; jt < 4; ++jt)
          mir[(w * 64 + jt * 16 + lo) * 20 + lq] = milo[jt] * n2i[jt];
    }
    __syncthreads();
    int offv0 = (d ? 100 : 20);
    for (int idx = tid; idx < 1280; idx += 256) {
      int i = idx / 20, lq = idx - i * 20;
      V1[((size_t)b * 64 + i) * 160 + offv0 + lq] = mjb[i * 20 + lq];
      float m = fmaxf(fmaxf(mir[(0 * 64 + i) * 20 + lq], mir[(1 * 64 + i) * 20 + lq]),
                      fmaxf(mir[(2 * 64 + i) * 20 + lq], mir[(3 * 64 + i) * 20 + lq]));
      V2[((size_t)b * 64 + i) * 160 + offv0 + lq] = m;
    }
  }
}

// ---------------- attention vectors: z=0 mean (MFMA), z=1 max ----------------
__global__ __launch_bounds__(256) void k_attn(const f16* __restrict__ O16,
        const f16* __restrict__ COS16, const float* __restrict__ RS,
        const float* __restrict__ CS, f16* __restrict__ MM16) {
  int b = blockIdx.x, v = blockIdx.y, mode = blockIdx.z;
  int d = v & 1, s2side = v >> 1;
  __shared__ f16 CT[64][72];
  __shared__ f16 ST[320][72];
  __shared__ f16 Cs[64][132];
  __shared__ unsigned int Ss[64][161];
  int tid = threadIdx.x;
  const unsigned int* Cp = (const unsigned int*)(COS16 + ((size_t)d * 32 + b) * 4096);
  int srcrec = s2side ? 0 : 2;
  const unsigned int* Sp = (const unsigned int*)(O16 + ((size_t)srcrec * 2048 + b * 64) * 320);

  if (mode == 0) {
    if (!s2side) {
      for (int idx = tid; idx < 2048; idx += 256) {
        int i = idx >> 5, jc = idx & 31;
        *(unsigned int*)(&CT[i][jc * 2]) = Cp[idx];
      }
    } else {
      for (int idx = tid; idx < 2048; idx += 256) {
        int i = idx >> 5, jc = idx & 31;
        union { unsigned int u; f16x2 h; } pk; pk.u = Cp[idx];
        CT[jc * 2][i] = pk.h[0];
        CT[jc * 2 + 1][i] = pk.h[1];
      }
    }
    for (int idx = tid; idx < 10240; idx += 256) {
      int k = idx / 160, c = idx - k * 160;
      union { unsigned int u; f16x2 h; } pk; pk.u = Sp[idx];
      ST[c * 2][k] = pk.h[0];
      ST[c * 2 + 1][k] = pk.h[1];
    }
    __syncthreads();
    int w = tid >> 6, l = tid & 63, lo = l & 15, hi = l >> 4;
    f32x4 acc[20] = {};
    #pragma unroll
    for (int kt = 0; kt < 2; ++kt) {
      f16x8 Af = *(const f16x8*)(&CT[w * 16 + lo][kt * 32 + hi * 8]);
      #pragma unroll
      for (int nt = 0; nt < 20; ++nt) {
        f16x8 Bfv = *(const f16x8*)(&ST[nt * 16 + lo][kt * 32 + hi * 8]);
        acc[nt] = __builtin_amdgcn_mfma_f32_16x16x32_f16(Af, Bfv, acc[nt], 0, 0, 0);
      }
    }
    const float* den = s2side ? CS : RS;
    float dv[4];
    #pragma unroll
    for (int r = 0; r < 4; ++r) dv[r] = den[(d * 32 + b) * 64 + w * 16 + hi * 4 + r];
    __syncthreads();
    f16 (*OT)[328] = (f16(*)[328])(&ST[0][0]);
    #pragma unroll
    for (int nt = 0; nt < 20; ++nt)
      #pragma unroll
      for (int r = 0; r < 4; ++r)
        OT[w * 16 + hi * 4 + r][nt * 16 + lo] = (f16)(acc[nt][r] / dv[r]);
    __syncthreads();
    unsigned int* Mp = (unsigned int*)(MM16 + ((size_t)v * 2048 + b * 64) * 320);
    for (int idx = tid; idx < 10240; idx += 256) {
      int m = idx / 160, c = idx - m * 160;
      union { f16x2 h; unsigned int u; } pk;
      pk.h[0] = OT[m][c * 2]; pk.h[1] = OT[m][c * 2 + 1];
      Mp[idx] = pk.u;
    }
  } else {
    for (int idx = tid; idx < 2048; idx += 256) {
      int i = idx >> 5, jc = idx & 31;
      *(unsigned int*)(&Cs[i][jc * 2]) = Cp[idx];
    }
    for (int idx = tid; idx < 10240; idx += 256) {
      int k = idx / 160, c = idx - k * 160;
      Ss[k][c] = Sp[idx];
    }
    __syncthreads();
    unsigned int* Mp = (unsigned int*)(MM16 + ((size_t)(4 + v) * 2048 + b * 64) * 320);
    for (int idx = tid; idx < 10240; idx += 256) {
      int r = idx / 160, c = idx - r * 160;
      f16 cv = s2side ? Cs[0][r] : Cs[r][0];
      union { unsigned int u; f16x2 h; } sv; sv.u = Ss[0][c];
      f16x2 cc; cc[0] = cv; cc[1] = cv;
      f16x2 mx = cc * sv.h;
      for (int inner = 1; inner < 64; ++inner) {
        f16 cv2 = s2side ? Cs[inner][r] : Cs[r][inner];
        sv.u = Ss[inner][c];
        f16x2 c2; c2[0] = cv2; c2[1] = cv2;
        f16x2 p = c2 * sv.h;
        mx[0] = p[0] > mx[0] ? p[0] : mx[0];
        mx[1] = p[1] > mx[1] ? p[1] : mx[1];
      }
      union { f16x2 h; unsigned int u; } o; o.h = mx;
      Mp[idx] = o.u;
    }
  }
}

// ---------------- MFMA full-match (12 variants), f16 inputs ----------------
__global__ __launch_bounds__(256) void k_fmm(const f16* __restrict__ O16,
        const f16* __restrict__ MM16, const f16* __restrict__ WSQ,
        float* __restrict__ V1, float* __restrict__ V2) {
  int ib = blockIdx.x, var = blockIdx.y;
  int tid = threadIdx.x;
  int w = tid >> 6, l = tid & 63, lo = l & 15, hi = l >> 4;
  int mt = w & 1, nt = w >> 1;
  __shared__ f16 Vs1[32][328];
  __shared__ f16 Vs2[32][328];
  __shared__ float zs[3][32][21];

  const f16* s1f = O16;
  const f16* s1b = O16 + (size_t)2048 * 320;
  const f16* s2f = O16 + (size_t)2 * 2048 * 320;
  const f16* s2b = O16 + (size_t)3 * 2048 * 320;
  const f16 *v1b, *v2b;
  int v2fix = 0, v2off = 0, wi, co;
  float* outbase;
  switch (var) {
    case 0:  v1b = s1f; v2b = s2f; v2fix = 1; v2off = 63; wi = 0; outbase = V1; co = 0;   break;
    case 1:  v1b = s1f; v2b = MM16 + (size_t)0 * 655360; wi = 2; outbase = V1; co = 40; break;
    case 2:  v1b = s1f; v2b = MM16 + (size_t)4 * 655360; wi = 3; outbase = V1; co = 60; break;
    case 3:  v1b = s1b; v2b = s2b; v2fix = 1; v2off = 0; wi = 1; outbase = V1; co = 80; break;
    case 4:  v1b = s1b; v2b = MM16 + (size_t)1 * 655360; wi = 2; outbase = V1; co = 120; break;
    case 5:  v1b = s1b; v2b = MM16 + (size_t)5 * 655360; wi = 3; outbase = V1; co = 140; break;
    case 6:  v1b = s2f; v2b = s1f; v2fix = 1; v2off = 63; wi = 0; outbase = V2; co = 0; break;
    case 7:  v1b = s2f; v2b = MM16 + (size_t)2 * 655360; wi = 2; outbase = V2; co = 40; break;
    case 8:  v1b = s2f; v2b = MM16 + (size_t)6 * 655360; wi = 3; outbase = V2; co = 60; break;
    case 9:  v1b = s2b; v2b = s1b; v2fix = 1; v2off = 0; wi = 1; outbase = V2; co = 80; break;
    case 10: v1b = s2b; v2b = MM16 + (size_t)3 * 655360; wi = 2; outbase = V2; co = 120; break;
    default: v1b = s2b; v2b = MM16 + (size_t)7 * 655360; wi = 3; outbase = V2; co = 140; break;
  }
  int srow = tid >> 3;
  int m1 = ib * 32 + srow;
  int m2 = v2fix ? (m1 & ~63) + v2off : m1;
  const unsigned int* r1 = (const unsigned int*)(v1b + (size_t)m1 * 320);
  const unsigned int* r2 = (const unsigned int*)(v2b + (size_t)m2 * 320);
  #pragma unroll
  for (int q = 0; q < 20; ++q) {
    int c = (tid & 7) + q * 8;
    *(unsigned int*)(&Vs1[srow][c * 2]) = r1[c];
    *(unsigned int*)(&Vs2[srow][c * 2]) = r2[c];
  }
  __syncthreads();

  const f16* Wv = WSQ + (size_t)wi * 10240;
  f32x4 acc[3] = {};
  #pragma unroll
  for (int kt = 0; kt < 10; ++kt) {
    f16x8 a1 = *(const f16x8*)(&Vs1[mt * 16 + lo][kt * 32 + hi * 8]);
    f16x8 a2 = *(const f16x8*)(&Vs2[mt * 16 + lo][kt * 32 + hi * 8]);
    f16x8 bf = *(const f16x8*)(Wv + ((size_t)(nt * 16 + lo)) * 320 + kt * 32 + hi * 8);
    acc[0] = __builtin_amdgcn_mfma_f32_16x16x32_f16(a1 * a2, bf, acc[0], 0, 0, 0);
    acc[1] = __builtin_amdgcn_mfma_f32_16x16x32_f16(a1 * a1, bf, acc[1], 0, 0, 0);
    acc[2] = __builtin_amdgcn_mfma_f32_16x16x32_f16(a2 * a2, bf, acc[2], 0, 0, 0);
  }
  #pragma unroll
  for (int pt = 0; pt < 3; ++pt)
    #pragma unroll
    for (int r = 0; r < 4; ++r) {
      int item = mt * 16 + hi * 4 + r, lcol = nt * 16 + lo;
      if (lcol < 20) zs[pt][item][lcol] = acc[pt][r];
    }
  __syncthreads();
  for (int idx = tid; idx < 640; idx += 256) {
    int item = idx / 20, lcol = idx - item * 20;
    float sn = zs[0][item][lcol], sa = zs[1][item][lcol], sb = zs[2][item][lcol];
    float o = sn / (fmaxf(sqrtf(sa), EPSF) * fmaxf(sqrtf(sb), EPSF));
    outbase[(size_t)(ib * 32 + item) * 160 + co + lcol] = o;
  }
}

// ---------------- MFMA hidden layer: XS = tanh(Hfin . W1h^T + b1) ----------
// Hfin = Hbuf parity-0: [32 chain][4 b][160 u32], chain = rec*8 + (b>>2).
__global__ __launch_bounds__(256) void k_mlpA(const unsigned int* __restrict__ Hp,
        const f16* __restrict__ W1h, const float* __restrict__ b1,
        float* __restrict__ XS) {
  __shared__ f16 Amat[32][1288];
  int tid = threadIdx.x;
  int n0 = blockIdx.x * 128;
  for (int i = tid; i < 20480; i += 256) {
    int rec = i / 5120, rem = i - rec * 5120;
    int b = rem / 160, uc = rem - b * 160;
    unsigned int v = Hp[(size_t)(rec * 8 + (b >> 2)) * 640 + (b & 3) * 160 + uc];
    *(unsigned int*)(&Amat[b][rec * 320 + uc * 2]) = v;
  }
  __syncthreads();
  int w = tid >> 6, l = tid & 63, lo = l & 15, hi = l >> 4;
  f32x4 acc[2][2] = {};
  for (int kt = 0; kt < 40; ++kt) {
    f16x8 Bf[2];
    #pragma unroll
    for (int nt = 0; nt < 2; ++nt) {
      int n = n0 + (w * 2 + nt) * 16 + lo;
      Bf[nt] = *(const f16x8*)(W1h + (size_t)n * 1280 + kt * 32 + hi * 8);
    }
    #pragma unroll
    for (int mt = 0; mt < 2; ++mt) {
      f16x8 Af = *(const f16x8*)(&Amat[mt * 16 + lo][kt * 32 + hi * 8]);
      #pragma unroll
      for (int nt = 0; nt < 2; ++nt)
        acc[mt][nt] = __builtin_amdgcn_mfma_f32_16x16x32_f16(Af, Bf[nt], acc[mt][nt], 0, 0, 0);
    }
  }
  #pragma unroll
  for (int mt = 0; mt < 2; ++mt)
    #pragma unroll
    for (int nt = 0; nt < 2; ++nt) {
      int n = n0 + (w * 2 + nt) * 16 + lo;
      if (n < 600) {
        float bias = b1[n];
        #pragma unroll
        for (int r = 0; r < 4; ++r) {
          int b = mt * 16 + hi * 4 + r;
          XS[(size_t)b * 600 + n] = ftanh(acc[mt][nt][r] + bias);
        }
      }
    }
}

// ---------------- logits + log_softmax ----------------
__global__ __launch_bounds__(64) void k_mlpB(const float* __restrict__ XS,
        const float* __restrict__ W2, const float* __restrict__ b2,
        float* __restrict__ out) {
  int b = blockIdx.x, lane = threadIdx.x;
  float p0 = 0.f, p1 = 0.f;
  for (int k = lane; k < 600; k += 64) {
    float xv = XS[(size_t)b * 600 + k];
    p0 += xv * W2[k];
    p1 += xv * W2[600 + k];
  }
  #pragma unroll
  for (int off = 32; off; off >>= 1) { p0 += __shfl_xor(p0, off); p1 += __shfl_xor(p1, off); }
  if (lane == 0) {
    float l0 = p0 + b2[0], l1 = p1 + b2[1];
    float m = fmaxf(l0, l1);
    float lse = m + logf(expf(l0 - m) + expf(l1 - m));
    out[b * 2 + 0] = l0 - lse;
    out[b * 2 + 1] = l1 - lse;
  }
}

extern "C" void kernel_launch(void* const* d_in, const int* in_sizes, int n_in,
                              void* d_out, int out_size, void* d_ws, size_t ws_size,
                              hipStream_t stream) {
  (void)in_sizes; (void)out_size;
  if (n_in < 25) return;
  const float* emb    = (const float*)d_in[0];
  const float* cWihF  = (const float*)d_in[1];
  const float* cWhhF  = (const float*)d_in[2];
  const float* cbF    = (const float*)d_in[3];
  const float* cWihB  = (const float*)d_in[4];
  const float* cWhhB  = (const float*)d_in[5];
  const float* cbB    = (const float*)d_in[6];
  const float* aWihF  = (const float*)d_in[7];
  const float* aWhhF  = (const float*)d_in[8];
  const float* abF    = (const float*)d_in[9];
  const float* aWihB  = (const float*)d_in[10];
  const float* aWhhB  = (const float*)d_in[11];
  const float* abB    = (const float*)d_in[12];
  const float* WfullF = (const float*)d_in[13];
  const float* WfullB = (const float*)d_in[14];
  const float* WmaxpF = (const float*)d_in[15];
  const float* WmaxpB = (const float*)d_in[16];
  const float* WattnF = (const float*)d_in[17];
  const float* WmaxaF = (const float*)d_in[18];
  const float* pW1    = (const float*)d_in[19];
  const float* pb1    = (const float*)d_in[20];
  const float* pW2    = (const float*)d_in[21];
  const float* pb2    = (const float*)d_in[22];
  const int*   sa     = (const int*)d_in[23];
  const int*   sb     = (const int*)d_in[24];
  float* out = (float*)d_out;
  float* ws = (float*)d_ws;

  // ---- workspace layout (float offsets) ----
  if (ws_size < (size_t)9302784 * 4) return;
  f16*   W1h  = (f16*)(ws + 0);                //  409600 fl
  float* XS   = ws + 409600;                   //   19200
  f16*   B16c = (f16*)(ws + 428800);           //  389120 fl
  f16*   B16a = (f16*)(ws + 817920);           //  194560 fl
  f16*   Wh16 = (f16*)(ws + 1012480);          //  819200 fl
  f16*   WSQ  = (f16*)(ws + 1831680);          //   30720 fl
  unsigned int* HbufA  = (unsigned int*)(ws + 1862400);  // 40960 u32
  unsigned int* flagsA = (unsigned int*)(ws + 1903360);  //  5120 u32
  unsigned int* HbufB  = (unsigned int*)(ws + 1908480);  // 40960 u32
  unsigned int* flagsB = (unsigned int*)(ws + 1949440);  //  5120 u32
  f16*   COS16 = (f16*)(ws + 1954560);         //  131072 fl
  float* RS   = ws + 2085632;                  //    4096
  float* CS   = ws + 2089728;                  //    4096
  float* V1   = ws + 2093824;                  //  327680
  float* V2   = ws + 2421504;                  //  327680
  unsigned int* O16u = (unsigned int*)(ws + 2749184);   // 1310720 fl
  f16*   O16  = (f16*)O16u;
  f16*   XG2  = (f16*)(ws + 4059904);          // 5242880 fl
  f16*   MM16 = XG2;                           //  alias (2621440 fl needed)

  f16* WhCtx = Wh16;
  f16* WhAgg = Wh16 + (size_t)2 * 409600;

  // ---- both H/flag regions zeroed up front (one memset, off critical path) ----
  hipMemsetAsync(HbufA, 0, 368640, stream);    // HbufA+flagsA+HbufB+flagsB

  // ---- unified weight prep ----
  k_prep<<<14400, 256, 0, stream>>>(cWhhF, cWhhB, aWhhF, aWhhB,
      cWihF, cWihB, aWihF, aWihB,
      WfullF, WfullB, WattnF, WmaxaF, WmaxpF, WmaxpB, pW1,
      Wh16, B16c, B16a, WSQ, W1h);

  // ---- context BiLSTM ----
  k_projm<<<dim3(16, 19, 2), 256, 0, stream>>>(emb, emb, sa, sb, B16c, cbF, cbB, XG2, 300, 320, 300);
  k_lstm11<<<320, 512, 0, stream>>>(WhCtx, XG2, HbufA, O16u, flagsA);

  // ---- matching ----
  k_cospair<<<dim3(32, 2, 2), 256, 0, stream>>>(O16, WSQ, COS16, RS, CS, V1, V2);
  k_attn<<<dim3(32, 4, 2), 256, 0, stream>>>(O16, COS16, RS, CS, MM16);
  k_fmm<<<dim3(64, 12), 256, 0, stream>>>(O16, MM16, WSQ, V1, V2);

  // ---- aggregation BiLSTM ----
  k_projm<<<dim3(16, 19, 2), 256, 0, stream>>>(V1, V2, nullptr, nullptr, B16a, abF, abB, XG2, 160, 160, 160);
  k_lstm11<<<320, 512, 0, stream>>>(WhAgg, XG2, HbufB, nullptr, flagsB);

  // ---- prediction head ----
  k_mlpA<<<5, 256, 0, stream>>>(HbufB, W1h, pb1, XS);
  k_mlpB<<<32, 64, 0, stream>>>(XS, pW2, pb2, out);
}